// Round 1
// baseline (3108.823 us; speedup 1.0000x reference)
//
#include <hip/hip_runtime.h>

#define NPTS 16384   // B*N = 8*2048
#define NB 2048
#define KNN 20

__device__ __forceinline__ float2 unpk_bf2(unsigned u){
    float2 r;
    r.x = __uint_as_float(u << 16);
    r.y = __uint_as_float(u & 0xffff0000u);
    return r;
}

// ---------------- weight prep ----------------
// pack fb2/fg1/fg2 (each 128x128 row-major [c][j]) into bf16 pairs:
// out[m*8192 + j2*128 + c] = bf16(W[c][2j2]) | bf16(W[c][2j2+1])<<16
__global__ void pack_w_kernel(const float* w0, const float* w1, const float* w2, unsigned* out){
    int gid = blockIdx.x*256 + threadIdx.x;
    if (gid >= 3*8192) return;
    int m = gid >> 13, r = gid & 8191;
    const float* W = (m==0) ? w0 : (m==1) ? w1 : w2;
    int c = r & 127, j2 = r >> 7;
    float a = W[c*128 + 2*j2], b = W[c*128 + 2*j2 + 1];
    unsigned ua = __float_as_uint(a); ua = (ua + 0x7fffu + ((ua>>16)&1u)) >> 16;
    unsigned ub = __float_as_uint(b); ub = (ub + 0x7fffu + ((ub>>16)&1u)) >> 16;
    out[gid] = ua | (ub << 16);
}

// transpose [C][128] -> [j][C]  (fp32), C = 128 or 32
__global__ void transpose_kernel(const float* in, float* out, int C){
    int gid = blockIdx.x*256 + threadIdx.x;
    if (gid >= 128*C) return;
    int j = gid / C, c = gid - j*C;
    out[gid] = in[c*128 + j];
}

// ---------------- kNN ----------------
__device__ __forceinline__ double dist2_of(int n, int j, const float* sx, const float* sy, const float* sz){
    double dx = (double)sx[j] - (double)sx[n];
    double dy = (double)sy[j] - (double)sy[n];
    double dz = (double)sz[j] - (double)sz[n];
    return dx*dx + dy*dy + dz*dz;
}
// better(a,b): candidate a ranks before b under top_k(pd) with pd=-d2 (desc, idx asc ties)
__device__ __forceinline__ bool knn_better(float va, int ja, float vb, int jb, int n,
                                           const float* sx, const float* sy, const float* sz){
    if (va != vb) return va > vb;
    if (ja == jb) return false;
    double da = dist2_of(n, ja, sx, sy, sz);
    double db = dist2_of(n, jb, sx, sy, sz);
    if (da != db) return da < db;
    return ja < jb;
}

__global__ __launch_bounds__(256) void knn_kernel(const float* feat, int* g_idx){
    __shared__ float sx[2048], sy[2048], sz[2048];     // 24 KB
    __shared__ float sval[256][20];                    // 20 KB
    __shared__ int   sidx[256][20];                    // 20 KB
    int tid = threadIdx.x;
    int p0 = blockIdx.x * 64;          // 64 points per block, same batch
    int b = p0 >> 11;
    const float* fb = feat + b*3*2048;
    for (int i = tid; i < 2048; i += 256){ sx[i]=fb[i]; sy[i]=fb[2048+i]; sz[i]=fb[4096+i]; }
#pragma unroll
    for (int k=0;k<20;k++){ sval[tid][k] = -3e38f; sidx[tid][k] = 0x7fffffff; }
    __syncthreads();
    int pl = tid & 63, chunk = tid >> 6;
    int n = (p0 + pl) & 2047;
    double xi = sx[n], yi = sy[n], zi = sz[n];
    for (int j = chunk*512; j < chunk*512 + 512; j++){
        double dx = (double)sx[j]-xi, dy = (double)sy[j]-yi, dz = (double)sz[j]-zi;
        double d2 = dx*dx + dy*dy + dz*dz;
        float vf = (float)(-d2);
        if (knn_better(vf, j, sval[tid][19], sidx[tid][19], n, sx, sy, sz)){
            int pos = 19;
            while (pos > 0){
                float pv = sval[tid][pos-1]; int pi = sidx[tid][pos-1];
                if (knn_better(vf, j, pv, pi, n, sx, sy, sz)){
                    sval[tid][pos] = pv; sidx[tid][pos] = pi; pos--;
                } else break;
            }
            sval[tid][pos] = vf; sidx[tid][pos] = j;
        }
    }
    __syncthreads();
    if (tid < 64){
        int nn = (p0 + tid) & 2047;
        int ptr[4] = {0,0,0,0};
        for (int kk=0; kk<20; kk++){
            float bv = 0.f; int bi = 0x7fffffff; int bc = -1;
#pragma unroll
            for (int c=0;c<4;c++){
                if (ptr[c] < 20){
                    int row = c*64 + tid;
                    float v = sval[row][ptr[c]]; int ix = sidx[row][ptr[c]];
                    if (bc < 0 || knn_better(v, ix, bv, bi, nn, sx, sy, sz)){ bv=v; bi=ix; bc=c; }
                }
            }
            ptr[bc]++;
            g_idx[(p0+tid)*20 + kk] = bi;
        }
    }
}

// ---------------- x1 = xt @ fc1.T + b ----------------
__global__ void x1_kernel(const float* feat, const float* w, const float* bias, float* x1){
    int gid = blockIdx.x*256 + threadIdx.x;   // 2,097,152
    int p = gid >> 7, c = gid & 127;
    int b = p >> 11, n = p & 2047;
    const float* fb = feat + b*6144 + n;
    float v = bias[c];
    v += w[c*3+0]*fb[0];
    v += w[c*3+1]*fb[2048];
    v += w[c*3+2]*fb[4096];
    x1[gid] = v;
}

// ---------------- q/k/v = x1 @ {wq,wk,wv}.T (transposed weights [j][c]) ----------------
__global__ __launch_bounds__(256) void qkv_kernel(const float* x1, const float* wqT, const float* wkT,
                                                  const float* wvT, float* q, float* k1, float* v1){
    __shared__ float sx[16][128];
    int tid = threadIdx.x;
    int p0 = blockIdx.x * 16;
    for (int t = tid; t < 2048; t += 256) sx[t>>7][t&127] = x1[p0*128 + t];
    __syncthreads();
    int cg = tid & 31, pg = tid >> 5, c0 = cg*4;
    float aq[2][4] = {{0,0,0,0},{0,0,0,0}};
    float ak[2][4] = {{0,0,0,0},{0,0,0,0}};
    float av[2][4] = {{0,0,0,0},{0,0,0,0}};
    for (int j=0;j<128;j++){
        float xa = sx[pg][j], xb = sx[pg+8][j];
        float4 wq4 = *(const float4*)&wqT[j*128 + c0];
        float4 wk4 = *(const float4*)&wkT[j*128 + c0];
        float4 wv4 = *(const float4*)&wvT[j*128 + c0];
        const float* wqp = &wq4.x; const float* wkp = &wk4.x; const float* wvp = &wv4.x;
#pragma unroll
        for (int ci=0; ci<4; ci++){
            aq[0][ci] += wqp[ci]*xa; aq[1][ci] += wqp[ci]*xb;
            ak[0][ci] += wkp[ci]*xa; ak[1][ci] += wkp[ci]*xb;
            av[0][ci] += wvp[ci]*xa; av[1][ci] += wvp[ci]*xb;
        }
    }
#pragma unroll
    for (int pp=0; pp<2; pp++){
        int p = p0 + pg + pp*8;
        *(float4*)&q [p*128 + c0] = make_float4(aq[pp][0],aq[pp][1],aq[pp][2],aq[pp][3]);
        *(float4*)&k1[p*128 + c0] = make_float4(ak[pp][0],ak[pp][1],ak[pp][2],ak[pp][3]);
        *(float4*)&v1[p*128 + c0] = make_float4(av[pp][0],av[pp][1],av[pp][2],av[pp][3]);
    }
}

// ---------------- fused edge/attention kernel ----------------
// block = 2 points x 128 threads. LDS <= 64KB.
__global__ __launch_bounds__(256) void attn_kernel(
        const float* feat, const int* g_idx, const float* g_q, const float* g_k1, const float* g_v1,
        const unsigned* wpk,                  // fb2(0), fg1(+8192), fg2(+16384) packed
        const float* fb1w, const float* fb1b, const float* fb2b, const float* fg1b, const float* fg2b,
        float* g_attn, float* g_res){
    __shared__ float sh_a [2][20][128];   // h -> a_in -> a2
    __shared__ float sh_t [2][20][128];
    __shared__ float sh_kf[2][20][128];
    __shared__ float sh_q [2][128];
    __shared__ float sh_e [2][20][6];
    __shared__ int   sh_ix[2][20];
    int tid = threadIdx.x;
    int p0 = blockIdx.x * 2;
    int pt = tid >> 7, t7 = tid & 127;
    int p = p0 + pt, b = p >> 11, n = p & 2047;
    sh_q[pt][t7] = g_q[p*128 + t7];
    if (t7 < 20) sh_ix[pt][t7] = g_idx[p*20 + t7];
    __syncthreads();
    if (t7 < 20){
        int nb = sh_ix[pt][t7];
        const float* fbp = feat + b*6144;
        float cx = fbp[n], cy = fbp[2048+n], cz = fbp[4096+n];
        float nx = fbp[nb], ny = fbp[2048+nb], nz = fbp[4096+nb];
        sh_e[pt][t7][0] = nx-cx; sh_e[pt][t7][1] = ny-cy; sh_e[pt][t7][2] = nz-cz;
        sh_e[pt][t7][3] = cx;    sh_e[pt][t7][4] = cy;    sh_e[pt][t7][5] = cz;
    }
    __syncthreads();

    int cg = t7 & 31, kg = t7 >> 5, c0 = cg*4;

    // P1: h = relu(fb1 . e + b1)
#pragma unroll
    for (int ci=0; ci<4; ci++){
        int c = c0 + ci;
        float w0=fb1w[c*6+0], w1=fb1w[c*6+1], w2=fb1w[c*6+2], w3=fb1w[c*6+3], w4=fb1w[c*6+4], w5=fb1w[c*6+5];
        float bb = fb1b[c];
#pragma unroll
        for (int ki=0; ki<5; ki++){
            int k = kg*5 + ki;
            float v = bb + w0*sh_e[pt][k][0] + w1*sh_e[pt][k][1] + w2*sh_e[pt][k][2]
                         + w3*sh_e[pt][k][3] + w4*sh_e[pt][k][4] + w5*sh_e[pt][k][5];
            sh_a[pt][k][c] = fmaxf(v, 0.f);
        }
    }
    __syncthreads();

    float acc[5][4];

    // P2: kf = fb2 . h + b2 ; a_in = q - kg + kf
#pragma unroll
    for (int ki=0;ki<5;ki++)
#pragma unroll
        for (int ci=0;ci<4;ci++) acc[ki][ci] = 0.f;
    {
        const unsigned* pw = wpk;
        for (int j2=0; j2<64; j2++){
            uint4 w = *(const uint4*)&pw[j2*128 + c0];
            float2 w0 = unpk_bf2(w.x), w1 = unpk_bf2(w.y), w2 = unpk_bf2(w.z), w3 = unpk_bf2(w.w);
#pragma unroll
            for (int ki=0; ki<5; ki++){
                float2 h2 = *(const float2*)&sh_a[pt][kg*5+ki][2*j2];
                acc[ki][0] += w0.x*h2.x + w0.y*h2.y;
                acc[ki][1] += w1.x*h2.x + w1.y*h2.y;
                acc[ki][2] += w2.x*h2.x + w2.y*h2.y;
                acc[ki][3] += w3.x*h2.x + w3.y*h2.y;
            }
        }
    }
    float ain[5][4];
    float4 b2v = *(const float4*)&fb2b[c0];
#pragma unroll
    for (int ki=0; ki<5; ki++){
        int k = kg*5 + ki;
        int nb = sh_ix[pt][k];
        float4 kv = *(const float4*)(g_k1 + (size_t)(b*2048 + nb)*128 + c0);
        const float* kvp = &kv.x; const float* bp = &b2v.x;
#pragma unroll
        for (int ci=0; ci<4; ci++){
            float kfv = acc[ki][ci] + bp[ci];
            sh_kf[pt][k][c0+ci] = kfv;
            ain[ki][ci] = sh_q[pt][c0+ci] - kvp[ci] + kfv;
        }
    }
    __syncthreads();
#pragma unroll
    for (int ki=0; ki<5; ki++)
#pragma unroll
        for (int ci=0; ci<4; ci++) sh_a[pt][kg*5+ki][c0+ci] = ain[ki][ci];
    __syncthreads();

    // P3: t = relu(fg1 . a_in + b)
#pragma unroll
    for (int ki=0;ki<5;ki++)
#pragma unroll
        for (int ci=0;ci<4;ci++) acc[ki][ci] = 0.f;
    {
        const unsigned* pw = wpk + 8192;
        for (int j2=0; j2<64; j2++){
            uint4 w = *(const uint4*)&pw[j2*128 + c0];
            float2 w0 = unpk_bf2(w.x), w1 = unpk_bf2(w.y), w2 = unpk_bf2(w.z), w3 = unpk_bf2(w.w);
#pragma unroll
            for (int ki=0; ki<5; ki++){
                float2 h2 = *(const float2*)&sh_a[pt][kg*5+ki][2*j2];
                acc[ki][0] += w0.x*h2.x + w0.y*h2.y;
                acc[ki][1] += w1.x*h2.x + w1.y*h2.y;
                acc[ki][2] += w2.x*h2.x + w2.y*h2.y;
                acc[ki][3] += w3.x*h2.x + w3.y*h2.y;
            }
        }
    }
    {
        float4 bg1 = *(const float4*)&fg1b[c0];
        const float* bp = &bg1.x;
#pragma unroll
        for (int ki=0; ki<5; ki++)
#pragma unroll
            for (int ci=0; ci<4; ci++)
                sh_t[pt][kg*5+ki][c0+ci] = fmaxf(acc[ki][ci] + bp[ci], 0.f);
    }
    __syncthreads();

    // P4: a2 = fg2 . t + b
#pragma unroll
    for (int ki=0;ki<5;ki++)
#pragma unroll
        for (int ci=0;ci<4;ci++) acc[ki][ci] = 0.f;
    {
        const unsigned* pw = wpk + 16384;
        for (int j2=0; j2<64; j2++){
            uint4 w = *(const uint4*)&pw[j2*128 + c0];
            float2 w0 = unpk_bf2(w.x), w1 = unpk_bf2(w.y), w2 = unpk_bf2(w.z), w3 = unpk_bf2(w.w);
#pragma unroll
            for (int ki=0; ki<5; ki++){
                float2 h2 = *(const float2*)&sh_t[pt][kg*5+ki][2*j2];
                acc[ki][0] += w0.x*h2.x + w0.y*h2.y;
                acc[ki][1] += w1.x*h2.x + w1.y*h2.y;
                acc[ki][2] += w2.x*h2.x + w2.y*h2.y;
                acc[ki][3] += w3.x*h2.x + w3.y*h2.y;
            }
        }
    }
    {
        float4 bg2 = *(const float4*)&fg2b[c0];
        const float* bp = &bg2.x;
#pragma unroll
        for (int ki=0; ki<5; ki++)
#pragma unroll
            for (int ci=0; ci<4; ci++)
                sh_a[pt][kg*5+ki][c0+ci] = acc[ki][ci] + bp[ci];
    }
    __syncthreads();

    // P5: log_softmax over K + attn write + res
    {
        int c = t7;
        float denom = sqrtf(128.0f);
        float s[20];
        float m = -3e38f;
#pragma unroll
        for (int k=0;k<20;k++){ s[k] = sh_a[pt][k][c] / denom; m = fmaxf(m, s[k]); }
        float sum = 0.f;
#pragma unroll
        for (int k=0;k<20;k++) sum += expf(s[k] - m);
        float L = m + logf(sum);
        float res = 0.f;
        float* op = g_attn + ((size_t)p*20)*128 + c;
#pragma unroll
        for (int k=0;k<20;k++){
            float at = s[k] - L;
            op[k*128] = at;
            int nb = sh_ix[pt][k];
            float vv = g_v1[(size_t)(b*2048 + nb)*128 + c];
            res += at * (vv + sh_kf[pt][k][c]);
        }
        g_res[p*128 + c] = res;
    }
}

// ---------------- generic per-point linear (128->128), transposed weight [j][c] ----------------
__global__ __launch_bounds__(256) void lin_kernel(const float* X, const float* WT, const float* bias, float* Y){
    __shared__ float sx[16][128];
    int tid = threadIdx.x;
    int p0 = blockIdx.x * 16;
    for (int t = tid; t < 2048; t += 256) sx[t>>7][t&127] = X[p0*128 + t];
    __syncthreads();
    int cg = tid & 31, pg = tid >> 5, c0 = cg*4;
    float a[2][4] = {{0,0,0,0},{0,0,0,0}};
    for (int j=0;j<128;j++){
        float xa = sx[pg][j], xb = sx[pg+8][j];
        float4 w4 = *(const float4*)&WT[j*128 + c0];
        const float* wp = &w4.x;
#pragma unroll
        for (int ci=0;ci<4;ci++){ a[0][ci] += wp[ci]*xa; a[1][ci] += wp[ci]*xb; }
    }
    float4 bv = *(const float4*)&bias[c0];
    const float* bp = &bv.x;
#pragma unroll
    for (int pp=0;pp<2;pp++){
        int p = p0 + pg + pp*8;
        *(float4*)&Y[p*128+c0] = make_float4(a[pp][0]+bp[0], a[pp][1]+bp[1], a[pp][2]+bp[2], a[pp][3]+bp[3]);
    }
}

// l6: Y = sa_t @ (Xa - Xb) + bias
__global__ __launch_bounds__(256) void l6_kernel(const float* Xa, const float* Xb, const float* WT,
                                                 const float* bias, float* Y){
    __shared__ float sx[16][128];
    int tid = threadIdx.x;
    int p0 = blockIdx.x * 16;
    for (int t = tid; t < 2048; t += 256) sx[t>>7][t&127] = Xa[p0*128 + t] - Xb[p0*128 + t];
    __syncthreads();
    int cg = tid & 31, pg = tid >> 5, c0 = cg*4;
    float a[2][4] = {{0,0,0,0},{0,0,0,0}};
    for (int j=0;j<128;j++){
        float xa = sx[pg][j], xb = sx[pg+8][j];
        float4 w4 = *(const float4*)&WT[j*128 + c0];
        const float* wp = &w4.x;
#pragma unroll
        for (int ci=0;ci<4;ci++){ a[0][ci] += wp[ci]*xa; a[1][ci] += wp[ci]*xb; }
    }
    float4 bv = *(const float4*)&bias[c0];
    const float* bp = &bv.x;
#pragma unroll
    for (int pp=0;pp<2;pp++){
        int p = p0 + pg + pp*8;
        *(float4*)&Y[p*128+c0] = make_float4(a[pp][0]+bp[0], a[pp][1]+bp[1], a[pp][2]+bp[2], a[pp][3]+bp[3]);
    }
}

// l5: xv = sa_v @ sres + b ; xqk = sa_qk @ sres
__global__ __launch_bounds__(256) void l5_kernel(const float* X, const float* WvT, const float* vb,
                                                 const float* WqkT, float* Yv, float* Yqk){
    __shared__ float sx[16][128];
    int tid = threadIdx.x;
    int p0 = blockIdx.x * 16;
    for (int t = tid; t < 2048; t += 256) sx[t>>7][t&127] = X[p0*128 + t];
    __syncthreads();
    int cg = tid & 31, pg = tid >> 5, c0 = cg*4;
    {
        float a[2][4] = {{0,0,0,0},{0,0,0,0}};
        for (int j=0;j<128;j++){
            float xa = sx[pg][j], xb = sx[pg+8][j];
            float4 w4 = *(const float4*)&WvT[j*128 + c0];
            const float* wp = &w4.x;
#pragma unroll
            for (int ci=0;ci<4;ci++){ a[0][ci] += wp[ci]*xa; a[1][ci] += wp[ci]*xb; }
        }
        float4 bv = *(const float4*)&vb[c0];
        const float* bp = &bv.x;
#pragma unroll
        for (int pp=0;pp<2;pp++){
            int p = p0 + pg + pp*8;
            *(float4*)&Yv[p*128+c0] = make_float4(a[pp][0]+bp[0], a[pp][1]+bp[1], a[pp][2]+bp[2], a[pp][3]+bp[3]);
        }
    }
    if (cg < 8){
        int cq = cg*4;
        float a[2][4] = {{0,0,0,0},{0,0,0,0}};
        for (int j=0;j<128;j++){
            float xa = sx[pg][j], xb = sx[pg+8][j];
            float4 w4 = *(const float4*)&WqkT[j*32 + cq];
            const float* wp = &w4.x;
#pragma unroll
            for (int ci=0;ci<4;ci++){ a[0][ci] += wp[ci]*xa; a[1][ci] += wp[ci]*xb; }
        }
#pragma unroll
        for (int pp=0;pp<2;pp++){
            int p = p0 + pg + pp*8;
            *(float4*)&Yqk[p*32+cq] = make_float4(a[pp][0], a[pp][1], a[pp][2], a[pp][3]);
        }
    }
}

// ---------------- batchnorm ----------------
__global__ void bn_stats_kernel(const float* X, float* sums){
    int tid = threadIdx.x;
    int c = tid & 127, half = tid >> 7;
    int r0 = blockIdx.x*128 + half*64;
    float s = 0.f, sq = 0.f;
    for (int r = r0; r < r0+64; r++){
        float v = X[r*128 + c];
        s += v; sq += v*v;
    }
    atomicAdd(&sums[c], s);
    atomicAdd(&sums[128+c], sq);
}

__global__ void bn1_apply_kernel(const float* res2, const float* x1, const float* sums,
                                 const float* g, const float* beta, float* sres){
    int gid = blockIdx.x*256 + threadIdx.x;
    int c = gid & 127;
    float mu = sums[c] * (1.0f/16384.f);
    float var = sums[128+c] * (1.0f/16384.f) - mu*mu;
    float inv = 1.0f / sqrtf(var + 1e-5f);
    float y = g[c]*(res2[gid]-mu)*inv + beta[c];
    sres[gid] = fmaxf(y, 0.f) + x1[gid];
}

__global__ void final_kernel(const float* sres, const float* xr2, const float* sums,
                             const float* g, const float* beta, float* out0){
    int gid = blockIdx.x*256 + threadIdx.x;
    int c = gid & 127;
    float mu = sums[c] * (1.0f/16384.f);
    float var = sums[128+c] * (1.0f/16384.f) - mu*mu;
    float inv = 1.0f / sqrtf(var + 1e-5f);
    float y = g[c]*(xr2[gid]-mu)*inv + beta[c];
    out0[gid] = sres[gid] + fmaxf(y, 0.f);
}

// ---------------- SA softmax row stats (2-pass recompute, LDS <= 34KB) ----------------
__global__ __launch_bounds__(256) void rowstats_kernel(const float* xqk, float* rm, float* rs){
    __shared__ float sxj[256][33];
    int tid = threadIdx.x;
    int b = blockIdx.x >> 8;
    int i0 = (blockIdx.x & 255) * 8;
    int ip = tid >> 6, l = tid & 63;
    const float* base = xqk + b*2048*32;
    float xi0[32], xi1[32];
#pragma unroll
    for (int c=0;c<32;c++){ xi0[c] = base[(i0+2*ip)*32+c]; xi1[c] = base[(i0+2*ip+1)*32+c]; }
    float m0 = -3e38f, m1 = -3e38f;
    for (int jc=0;jc<8;jc++){
        __syncthreads();
        for (int t=tid;t<8192;t+=256) sxj[t>>5][t&31] = base[jc*8192 + t];
        __syncthreads();
        for (int s=0;s<4;s++){
            int j = l + s*64;
            float d0=0.f, d1=0.f;
#pragma unroll
            for (int c=0;c<32;c++){ float xv = sxj[j][c]; d0 += xi0[c]*xv; d1 += xi1[c]*xv; }
            m0 = fmaxf(m0, d0); m1 = fmaxf(m1, d1);
        }
    }
#pragma unroll
    for (int mk=32; mk>=1; mk>>=1){ m0 = fmaxf(m0, __shfl_xor(m0,mk)); m1 = fmaxf(m1, __shfl_xor(m1,mk)); }
    float s0 = 0.f, s1 = 0.f;
    for (int jc=0;jc<8;jc++){
        __syncthreads();
        for (int t=tid;t<8192;t+=256) sxj[t>>5][t&31] = base[jc*8192 + t];
        __syncthreads();
        for (int s=0;s<4;s++){
            int j = l + s*64;
            float d0=0.f, d1=0.f;
#pragma unroll
            for (int c=0;c<32;c++){ float xv = sxj[j][c]; d0 += xi0[c]*xv; d1 += xi1[c]*xv; }
            s0 += expf(d0 - m0); s1 += expf(d1 - m1);
        }
    }
#pragma unroll
    for (int mk=32; mk>=1; mk>>=1){ s0 += __shfl_xor(s0,mk); s1 += __shfl_xor(s1,mk); }
    if (l == 0){
        rm[b*2048+i0+2*ip]   = m0; rs[b*2048+i0+2*ip]   = s0;
        rm[b*2048+i0+2*ip+1] = m1; rs[b*2048+i0+2*ip+1] = s1;
    }
}

__global__ __launch_bounds__(256) void colsum_kernel(const float* xqk, const float* rm, const float* rs, float* cs){
    __shared__ float sxi[256][33];
    __shared__ float srm[256], sirs[256];
    int tid = threadIdx.x;
    int blk = blockIdx.x;                 // 8b * 8jt * 8ic = 512
    int b = blk >> 6, jt = (blk>>3)&7, ic = blk&7;
    const float* base = xqk + b*2048*32;
    int j = jt*256 + tid;
    float xj[32];
#pragma unroll
    for (int c=0;c<32;c++) xj[c] = base[j*32+c];
    int i0 = ic*256;
    for (int t=tid;t<8192;t+=256) sxi[t>>5][t&31] = base[i0*32 + t];
    srm[tid] = rm[b*2048 + i0 + tid];
    sirs[tid] = 1.0f / rs[b*2048 + i0 + tid];
    __syncthreads();
    float acc = 0.f;
    for (int i=0;i<256;i++){
        float d = 0.f;
#pragma unroll
        for (int c=0;c<32;c++) d += sxi[i][c]*xj[c];
        acc += expf(d - srm[i]) * sirs[i];
    }
    atomicAdd(&cs[b*2048 + j], acc);
}

// xr[m][c] = (sum_n att[n][m] * xv[n][c]) / (1e-9 + colsum[m]),  att recomputed on the fly
__global__ __launch_bounds__(256) void xr_kernel(const float* xqk, const float* xv, const float* rm,
                                                 const float* rs, const float* cs, float* xr){
    __shared__ float sqm[32][33];
    __shared__ float sqn[64][33];
    __shared__ float sxv[64][128];
    __shared__ float satt[64][32];
    __shared__ float srm[64], sirs[64], sics[32];
    int tid = threadIdx.x;
    int b = blockIdx.x >> 6, mt = blockIdx.x & 63;
    const float* qb = xqk + b*2048*32;
    for (int t=tid; t<1024; t+=256) sqm[t>>5][t&31] = qb[(mt*32)*32 + t];
    if (tid < 32) sics[tid] = 1.0f / (1e-9f + cs[b*2048 + mt*32 + tid]);
    float acc[4][4];
#pragma unroll
    for (int i=0;i<4;i++)
#pragma unroll
        for (int jj=0;jj<4;jj++) acc[i][jj] = 0.f;
    int mg = tid >> 5, cgx = tid & 31, m0 = mg*4, c0 = cgx*4;
    int nq = tid >> 2, mq = tid & 3;
    for (int nc=0; nc<32; nc++){
        int n0 = nc*64;
        __syncthreads();
        for (int t=tid; t<2048; t+=256) sqn[t>>5][t&31] = qb[n0*32 + t];
        for (int t=tid; t<2048; t+=256){
            int r = t>>5, cq = (t&31)*4;
            *(float4*)&sxv[r][cq] = *(const float4*)&xv[(size_t)(b*2048+n0+r)*128 + cq];
        }
        if (tid < 64){ srm[tid] = rm[b*2048+n0+tid]; sirs[tid] = 1.0f/rs[b*2048+n0+tid]; }
        __syncthreads();
        {
            float qn[32];
#pragma unroll
            for (int c=0;c<32;c++) qn[c] = sqn[nq][c];
            float rmv = srm[nq], irsv = sirs[nq];
            float av[8];
#pragma unroll
            for (int mi=0;mi<8;mi++){
                int m = mq*8+mi;
                float d = 0.f;
#pragma unroll
                for (int c=0;c<32;c++) d += qn[c]*sqm[m][c];
                av[mi] = expf(d - rmv) * irsv;
            }
            *(float4*)&satt[nq][mq*8]   = make_float4(av[0],av[1],av[2],av[3]);
            *(float4*)&satt[nq][mq*8+4] = make_float4(av[4],av[5],av[6],av[7]);
        }
        __syncthreads();
        for (int nn=0; nn<64; nn++){
            float4 a4 = *(const float4*)&satt[nn][m0];
            float4 x4 = *(const float4*)&sxv[nn][c0];
            const float* ap = &a4.x; const float* xp = &x4.x;
#pragma unroll
            for (int mi=0;mi<4;mi++)
#pragma unroll
                for (int ci=0;ci<4;ci++) acc[mi][ci] += ap[mi]*xp[ci];
        }
    }
#pragma unroll
    for (int mi=0;mi<4;mi++){
        float sc = sics[m0+mi];
        *(float4*)&xr[(size_t)(b*2048 + mt*32 + m0+mi)*128 + c0] =
            make_float4(acc[mi][0]*sc, acc[mi][1]*sc, acc[mi][2]*sc, acc[mi][3]*sc);
    }
}

// ---------------- launch ----------------
extern "C" void kernel_launch(void* const* d_in, const int* in_sizes, int n_in,
                              void* d_out, int out_size, void* d_ws, size_t ws_size,
                              hipStream_t stream){
    (void)in_sizes; (void)n_in; (void)out_size; (void)ws_size;
    const float* feat = (const float*)d_in[0];
    const float* fc1w = (const float*)d_in[1];  const float* fc1b = (const float*)d_in[2];
    const float* fc2w = (const float*)d_in[3];  const float* fc2b = (const float*)d_in[4];
    const float* bng  = (const float*)d_in[5];  const float* bnb  = (const float*)d_in[6];
    const float* fb1w = (const float*)d_in[7];  const float* fb1b = (const float*)d_in[8];
    const float* fb2w = (const float*)d_in[9];  const float* fb2b = (const float*)d_in[10];
    const float* fg1w = (const float*)d_in[11]; const float* fg1b = (const float*)d_in[12];
    const float* fg2w = (const float*)d_in[13]; const float* fg2b = (const float*)d_in[14];
    const float* wq   = (const float*)d_in[15]; const float* wk   = (const float*)d_in[16];
    const float* wv   = (const float*)d_in[17];
    const float* saqk = (const float*)d_in[18];
    const float* savw = (const float*)d_in[19]; const float* savb = (const float*)d_in[20];
    const float* satw = (const float*)d_in[21]; const float* satb = (const float*)d_in[22];
    const float* sabng= (const float*)d_in[23]; const float* sabnb= (const float*)d_in[24];

    float* out0 = (float*)d_out;
    float* out1 = out0 + 2097152;

    char* ws = (char*)d_ws;
    size_t off = 0;
    auto A = [&](size_t bytes)->char*{
        char* r = ws + off;
        off = (off + bytes + 255) & ~(size_t)255;
        return r;
    };
    const size_t PBUF = (size_t)NPTS*128*4;   // 8 MB
    int*      g_idx  = (int*)A((size_t)NPTS*KNN*4);
    float*    g_x1   = (float*)A(PBUF);
    float*    g_q    = (float*)A(PBUF);
    float*    g_k1   = (float*)A(PBUF);
    float*    g_v1   = (float*)A(PBUF);
    float*    g_res  = (float*)A(PBUF);
    float*    g_res2 = (float*)A(PBUF);
    float*    g_sres = (float*)A(PBUF);
    float*    g_xv   = (float*)A(PBUF);
    float*    g_xr   = (float*)A(PBUF);
    float*    g_xr2  = (float*)A(PBUF);
    float*    g_xqk  = (float*)A((size_t)NPTS*32*4);
    float*    g_rm   = (float*)A((size_t)NPTS*4);
    float*    g_rs   = (float*)A((size_t)NPTS*4);
    float*    g_stats= (float*)A((size_t)(256+256+NPTS)*4);  // bn1(256) bn2(256) colsum(16384)
    unsigned* g_wpk  = (unsigned*)A((size_t)3*8192*4);
    float*    g_wqT  = (float*)A(65536);
    float*    g_wkT  = (float*)A(65536);
    float*    g_wvT  = (float*)A(65536);
    float*    g_fc2T = (float*)A(65536);
    float*    g_savT = (float*)A(65536);
    float*    g_satT = (float*)A(65536);
    float*    g_sqkT = (float*)A(16384);

    float* bn1s = g_stats;
    float* bn2s = g_stats + 256;
    float* g_cs = g_stats + 512;

    hipMemsetAsync(g_stats, 0, (size_t)(256+256+NPTS)*4, stream);

    pack_w_kernel<<<96, 256, 0, stream>>>(fb2w, fg1w, fg2w, g_wpk);
    transpose_kernel<<<64, 256, 0, stream>>>(wq,   g_wqT, 128);
    transpose_kernel<<<64, 256, 0, stream>>>(wk,   g_wkT, 128);
    transpose_kernel<<<64, 256, 0, stream>>>(wv,   g_wvT, 128);
    transpose_kernel<<<64, 256, 0, stream>>>(fc2w, g_fc2T, 128);
    transpose_kernel<<<64, 256, 0, stream>>>(savw, g_savT, 128);
    transpose_kernel<<<64, 256, 0, stream>>>(satw, g_satT, 128);
    transpose_kernel<<<16, 256, 0, stream>>>(saqk, g_sqkT, 32);

    knn_kernel<<<256, 256, 0, stream>>>(feat, g_idx);
    x1_kernel<<<8192, 256, 0, stream>>>(feat, fc1w, fc1b, g_x1);
    qkv_kernel<<<1024, 256, 0, stream>>>(g_x1, g_wqT, g_wkT, g_wvT, g_q, g_k1, g_v1);
    attn_kernel<<<8192, 256, 0, stream>>>(feat, g_idx, g_q, g_k1, g_v1, g_wpk,
                                          fb1w, fb1b, fb2b, fg1b, fg2b, out1, g_res);
    lin_kernel<<<1024, 256, 0, stream>>>(g_res, g_fc2T, fc2b, g_res2);
    bn_stats_kernel<<<128, 256, 0, stream>>>(g_res2, bn1s);
    bn1_apply_kernel<<<8192, 256, 0, stream>>>(g_res2, g_x1, bn1s, bng, bnb, g_sres);
    l5_kernel<<<1024, 256, 0, stream>>>(g_sres, g_savT, savb, g_sqkT, g_xv, g_xqk);
    rowstats_kernel<<<2048, 256, 0, stream>>>(g_xqk, g_rm, g_rs);
    colsum_kernel<<<512, 256, 0, stream>>>(g_xqk, g_rm, g_rs, g_cs);
    xr_kernel<<<512, 256, 0, stream>>>(g_xqk, g_xv, g_rm, g_rs, g_cs, g_xr);
    l6_kernel<<<1024, 256, 0, stream>>>(g_sres, g_xr, g_satT, satb, g_xr2);
    bn_stats_kernel<<<128, 256, 0, stream>>>(g_xr2, bn2s);
    final_kernel<<<8192, 256, 0, stream>>>(g_sres, g_xr2, bn2s, sabng, sabnb, out0);
}

// Round 2
// 1661.311 us; speedup vs baseline: 1.8713x; 1.8713x over previous
//
#include <hip/hip_runtime.h>

#define NPTS 16384   // B*N = 8*2048
#define NB 2048
#define KNN 20

// transpose [C][128] -> [j][C]  (fp32), C = 128 or 32
__global__ void transpose_kernel(const float* in, float* out, int C){
    int gid = blockIdx.x*256 + threadIdx.x;
    if (gid >= 128*C) return;
    int j = gid / C, c = gid - j*C;
    out[gid] = in[c*128 + j];
}

// ---------------- kNN ----------------
__device__ __forceinline__ double dist2_of(int n, int j, const float* sx, const float* sy, const float* sz){
    j &= 2047;  // guard LDS OOB for sentinel idx under if-conversion (result unused then)
    double dx = (double)sx[j] - (double)sx[n];
    double dy = (double)sy[j] - (double)sy[n];
    double dz = (double)sz[j] - (double)sz[n];
    return dx*dx + dy*dy + dz*dz;
}
// better(a,b): candidate a ranks before b under top_k(pd) with pd=-d2 (desc, idx asc ties)
__device__ __forceinline__ bool knn_better(float va, int ja, float vb, int jb, int n,
                                           const float* sx, const float* sy, const float* sz){
    if (va != vb) return va > vb;
    if (ja == jb) return false;
    double da = dist2_of(n, ja, sx, sy, sz);
    double db = dist2_of(n, jb, sx, sy, sz);
    if (da != db) return da < db;
    return ja < jb;
}

__global__ __launch_bounds__(256) void knn_kernel(const float* feat, int* g_idx){
    __shared__ float sx[2048], sy[2048], sz[2048];     // 24 KB
    __shared__ float sval[256][20];                    // 20 KB
    __shared__ int   sidx[256][20];                    // 20 KB
    int tid = threadIdx.x;
    int p0 = blockIdx.x * 64;          // 64 points per block, same batch
    int b = p0 >> 11;
    const float* fb = feat + b*3*2048;
    for (int i = tid; i < 2048; i += 256){ sx[i]=fb[i]; sy[i]=fb[2048+i]; sz[i]=fb[4096+i]; }
    __syncthreads();
    int pl = tid & 63, chunk = tid >> 6;
    int n = (p0 + pl) & 2047;
    double xi = sx[n], yi = sy[n], zi = sz[n];

    // register top-20, sorted best(0) -> worst(19)
    float val[20]; int idx[20];
#pragma unroll
    for (int k=0;k<20;k++){ val[k] = -3e38f; idx[k] = 0x7fffffff; }

    for (int j = chunk*512; j < chunk*512 + 512; j++){
        double dx = (double)sx[j]-xi, dy = (double)sy[j]-yi, dz = (double)sz[j]-zi;
        double d2 = dx*dx + dy*dy + dz*dz;
        float vf = (float)(-d2);
        bool tie = false;
#pragma unroll
        for (int s=0;s<20;s++) tie |= (vf == val[s]);
        if (!tie){
            // branch-free insert, strict key compare (exact: keys all distinct here)
            bool bs = vf > val[19];
#pragma unroll
            for (int s=19; s>=1; s--){
                bool bm = vf > val[s-1];
                float nv = bm ? val[s-1] : vf;
                int   ni = bm ? idx[s-1] : j;
                val[s] = bs ? nv : val[s];
                idx[s] = bs ? ni : idx[s];
                bs = bm;
            }
            val[0] = bs ? vf : val[0];
            idx[0] = bs ? j  : idx[0];
        } else {
            // rare: fp32-key tie somewhere -> full comparator (fp64 refine + idx)
            bool bs = knn_better(vf, j, val[19], idx[19], n, sx, sy, sz);
#pragma unroll
            for (int s=19; s>=1; s--){
                bool bm = knn_better(vf, j, val[s-1], idx[s-1], n, sx, sy, sz);
                float nv = bm ? val[s-1] : vf;
                int   ni = bm ? idx[s-1] : j;
                val[s] = bs ? nv : val[s];
                idx[s] = bs ? ni : idx[s];
                bs = bm;
            }
            val[0] = bs ? vf : val[0];
            idx[0] = bs ? j  : idx[0];
        }
    }
#pragma unroll
    for (int k=0;k<20;k++){ sval[tid][k] = val[k]; sidx[tid][k] = idx[k]; }
    __syncthreads();
    if (tid < 64){
        int nn = (p0 + tid) & 2047;
        int ptr[4] = {0,0,0,0};
        for (int kk=0; kk<20; kk++){
            float bv = 0.f; int bi = 0x7fffffff; int bc = -1;
#pragma unroll
            for (int c=0;c<4;c++){
                if (ptr[c] < 20){
                    int row = c*64 + tid;
                    float v = sval[row][ptr[c]]; int ix = sidx[row][ptr[c]];
                    if (bc < 0 || knn_better(v, ix, bv, bi, nn, sx, sy, sz)){ bv=v; bi=ix; bc=c; }
                }
            }
            ptr[bc]++;
            g_idx[(p0+tid)*20 + kk] = bi;
        }
    }
}

// ---------------- x1 = xt @ fc1.T + b ----------------
__global__ void x1_kernel(const float* feat, const float* w, const float* bias, float* x1){
    int gid = blockIdx.x*256 + threadIdx.x;   // 2,097,152
    int p = gid >> 7, c = gid & 127;
    int b = p >> 11, n = p & 2047;
    const float* fb = feat + b*6144 + n;
    float v = bias[c];
    v += w[c*3+0]*fb[0];
    v += w[c*3+1]*fb[2048];
    v += w[c*3+2]*fb[4096];
    x1[gid] = v;
}

// ---------------- q/k/v = x1 @ {wq,wk,wv}.T (transposed weights [j][c]) ----------------
__global__ __launch_bounds__(256) void qkv_kernel(const float* x1, const float* wqT, const float* wkT,
                                                  const float* wvT, float* q, float* k1, float* v1){
    __shared__ float sx[16][128];
    int tid = threadIdx.x;
    int p0 = blockIdx.x * 16;
    for (int t = tid; t < 2048; t += 256) sx[t>>7][t&127] = x1[p0*128 + t];
    __syncthreads();
    int cg = tid & 31, pg = tid >> 5, c0 = cg*4;
    float aq[2][4] = {{0,0,0,0},{0,0,0,0}};
    float ak[2][4] = {{0,0,0,0},{0,0,0,0}};
    float av[2][4] = {{0,0,0,0},{0,0,0,0}};
    for (int j=0;j<128;j++){
        float xa = sx[pg][j], xb = sx[pg+8][j];
        float4 wq4 = *(const float4*)&wqT[j*128 + c0];
        float4 wk4 = *(const float4*)&wkT[j*128 + c0];
        float4 wv4 = *(const float4*)&wvT[j*128 + c0];
        const float* wqp = &wq4.x; const float* wkp = &wk4.x; const float* wvp = &wv4.x;
#pragma unroll
        for (int ci=0; ci<4; ci++){
            aq[0][ci] += wqp[ci]*xa; aq[1][ci] += wqp[ci]*xb;
            ak[0][ci] += wkp[ci]*xa; ak[1][ci] += wkp[ci]*xb;
            av[0][ci] += wvp[ci]*xa; av[1][ci] += wvp[ci]*xb;
        }
    }
#pragma unroll
    for (int pp=0; pp<2; pp++){
        int p = p0 + pg + pp*8;
        *(float4*)&q [p*128 + c0] = make_float4(aq[pp][0],aq[pp][1],aq[pp][2],aq[pp][3]);
        *(float4*)&k1[p*128 + c0] = make_float4(ak[pp][0],ak[pp][1],ak[pp][2],ak[pp][3]);
        *(float4*)&v1[p*128 + c0] = make_float4(av[pp][0],av[pp][1],av[pp][2],av[pp][3]);
    }
}

// ---------------- fused edge/attention kernel ----------------
// block = 2 points x 128 threads. LDS <= 64KB. fp32 weights (transposed [j][c]).
__global__ __launch_bounds__(256) void attn_kernel(
        const float* feat, const int* g_idx, const float* g_q, const float* g_k1, const float* g_v1,
        const float* fb2T, const float* fg1T, const float* fg2T,
        const float* fb1w, const float* fb1b, const float* fb2b, const float* fg1b, const float* fg2b,
        float* g_attn, float* g_res){
    __shared__ float sh_a [2][20][128];   // h -> a_in -> a2
    __shared__ float sh_t [2][20][128];
    __shared__ float sh_kf[2][20][128];
    __shared__ float sh_q [2][128];
    __shared__ float sh_e [2][20][6];
    __shared__ int   sh_ix[2][20];
    int tid = threadIdx.x;
    int p0 = blockIdx.x * 2;
    int pt = tid >> 7, t7 = tid & 127;
    int p = p0 + pt, b = p >> 11, n = p & 2047;
    sh_q[pt][t7] = g_q[p*128 + t7];
    if (t7 < 20) sh_ix[pt][t7] = g_idx[p*20 + t7];
    __syncthreads();
    if (t7 < 20){
        int nb = sh_ix[pt][t7];
        const float* fbp = feat + b*6144;
        float cx = fbp[n], cy = fbp[2048+n], cz = fbp[4096+n];
        float nx = fbp[nb], ny = fbp[2048+nb], nz = fbp[4096+nb];
        sh_e[pt][t7][0] = nx-cx; sh_e[pt][t7][1] = ny-cy; sh_e[pt][t7][2] = nz-cz;
        sh_e[pt][t7][3] = cx;    sh_e[pt][t7][4] = cy;    sh_e[pt][t7][5] = cz;
    }
    __syncthreads();

    int cg = t7 & 31, kg = t7 >> 5, c0 = cg*4;

    // P1: h = relu(fb1 . e + b1)
#pragma unroll
    for (int ci=0; ci<4; ci++){
        int c = c0 + ci;
        float w0=fb1w[c*6+0], w1=fb1w[c*6+1], w2=fb1w[c*6+2], w3=fb1w[c*6+3], w4=fb1w[c*6+4], w5=fb1w[c*6+5];
        float bb = fb1b[c];
#pragma unroll
        for (int ki=0; ki<5; ki++){
            int k = kg*5 + ki;
            float v = bb + w0*sh_e[pt][k][0] + w1*sh_e[pt][k][1] + w2*sh_e[pt][k][2]
                         + w3*sh_e[pt][k][3] + w4*sh_e[pt][k][4] + w5*sh_e[pt][k][5];
            sh_a[pt][k][c] = fmaxf(v, 0.f);
        }
    }
    __syncthreads();

    float acc[5][4];

    // P2: kf = fb2 . h + b2 ; a_in = q - kg + kf
#pragma unroll
    for (int ki=0;ki<5;ki++)
#pragma unroll
        for (int ci=0;ci<4;ci++) acc[ki][ci] = 0.f;
    for (int j=0;j<128;j++){
        float4 w = *(const float4*)&fb2T[j*128 + c0];
#pragma unroll
        for (int ki=0; ki<5; ki++){
            float h = sh_a[pt][kg*5+ki][j];
            acc[ki][0] += w.x*h; acc[ki][1] += w.y*h; acc[ki][2] += w.z*h; acc[ki][3] += w.w*h;
        }
    }
    float ain[5][4];
    float4 b2v = *(const float4*)&fb2b[c0];
#pragma unroll
    for (int ki=0; ki<5; ki++){
        int k = kg*5 + ki;
        int nb = sh_ix[pt][k];
        float4 kv = *(const float4*)(g_k1 + (size_t)(b*2048 + nb)*128 + c0);
        const float* kvp = &kv.x; const float* bp = &b2v.x;
#pragma unroll
        for (int ci=0; ci<4; ci++){
            float kfv = acc[ki][ci] + bp[ci];
            sh_kf[pt][k][c0+ci] = kfv;
            ain[ki][ci] = sh_q[pt][c0+ci] - kvp[ci] + kfv;
        }
    }
    __syncthreads();
#pragma unroll
    for (int ki=0; ki<5; ki++)
#pragma unroll
        for (int ci=0; ci<4; ci++) sh_a[pt][kg*5+ki][c0+ci] = ain[ki][ci];
    __syncthreads();

    // P3: t = relu(fg1 . a_in + b)
#pragma unroll
    for (int ki=0;ki<5;ki++)
#pragma unroll
        for (int ci=0;ci<4;ci++) acc[ki][ci] = 0.f;
    for (int j=0;j<128;j++){
        float4 w = *(const float4*)&fg1T[j*128 + c0];
#pragma unroll
        for (int ki=0; ki<5; ki++){
            float h = sh_a[pt][kg*5+ki][j];
            acc[ki][0] += w.x*h; acc[ki][1] += w.y*h; acc[ki][2] += w.z*h; acc[ki][3] += w.w*h;
        }
    }
    {
        float4 bg1 = *(const float4*)&fg1b[c0];
        const float* bp = &bg1.x;
#pragma unroll
        for (int ki=0; ki<5; ki++)
#pragma unroll
            for (int ci=0; ci<4; ci++)
                sh_t[pt][kg*5+ki][c0+ci] = fmaxf(acc[ki][ci] + bp[ci], 0.f);
    }
    __syncthreads();

    // P4: a2 = fg2 . t + b
#pragma unroll
    for (int ki=0;ki<5;ki++)
#pragma unroll
        for (int ci=0;ci<4;ci++) acc[ki][ci] = 0.f;
    for (int j=0;j<128;j++){
        float4 w = *(const float4*)&fg2T[j*128 + c0];
#pragma unroll
        for (int ki=0; ki<5; ki++){
            float h = sh_t[pt][kg*5+ki][j];
            acc[ki][0] += w.x*h; acc[ki][1] += w.y*h; acc[ki][2] += w.z*h; acc[ki][3] += w.w*h;
        }
    }
    {
        float4 bg2 = *(const float4*)&fg2b[c0];
        const float* bp = &bg2.x;
#pragma unroll
        for (int ki=0; ki<5; ki++)
#pragma unroll
            for (int ci=0; ci<4; ci++)
                sh_a[pt][kg*5+ki][c0+ci] = acc[ki][ci] + bp[ci];
    }
    __syncthreads();

    // P5: log_softmax over K + attn write + res
    {
        int c = t7;
        float denom = sqrtf(128.0f);
        float s[20];
        float m = -3e38f;
#pragma unroll
        for (int k=0;k<20;k++){ s[k] = sh_a[pt][k][c] / denom; m = fmaxf(m, s[k]); }
        float sum = 0.f;
#pragma unroll
        for (int k=0;k<20;k++) sum += expf(s[k] - m);
        float L = m + logf(sum);
        float res = 0.f;
        float* op = g_attn + ((size_t)p*20)*128 + c;
#pragma unroll
        for (int k=0;k<20;k++){
            float at = s[k] - L;
            op[k*128] = at;
            int nb = sh_ix[pt][k];
            float vv = g_v1[(size_t)(b*2048 + nb)*128 + c];
            res += at * (vv + sh_kf[pt][k][c]);
        }
        g_res[p*128 + c] = res;
    }
}

// ---------------- generic per-point linear (128->128), transposed weight [j][c] ----------------
__global__ __launch_bounds__(256) void lin_kernel(const float* X, const float* WT, const float* bias, float* Y){
    __shared__ float sx[16][128];
    int tid = threadIdx.x;
    int p0 = blockIdx.x * 16;
    for (int t = tid; t < 2048; t += 256) sx[t>>7][t&127] = X[p0*128 + t];
    __syncthreads();
    int cg = tid & 31, pg = tid >> 5, c0 = cg*4;
    float a[2][4] = {{0,0,0,0},{0,0,0,0}};
    for (int j=0;j<128;j++){
        float xa = sx[pg][j], xb = sx[pg+8][j];
        float4 w4 = *(const float4*)&WT[j*128 + c0];
        const float* wp = &w4.x;
#pragma unroll
        for (int ci=0;ci<4;ci++){ a[0][ci] += wp[ci]*xa; a[1][ci] += wp[ci]*xb; }
    }
    float4 bv = *(const float4*)&bias[c0];
    const float* bp = &bv.x;
#pragma unroll
    for (int pp=0;pp<2;pp++){
        int p = p0 + pg + pp*8;
        *(float4*)&Y[p*128+c0] = make_float4(a[pp][0]+bp[0], a[pp][1]+bp[1], a[pp][2]+bp[2], a[pp][3]+bp[3]);
    }
}

// l6: Y = sa_t @ (Xa - Xb) + bias
__global__ __launch_bounds__(256) void l6_kernel(const float* Xa, const float* Xb, const float* WT,
                                                 const float* bias, float* Y){
    __shared__ float sx[16][128];
    int tid = threadIdx.x;
    int p0 = blockIdx.x * 16;
    for (int t = tid; t < 2048; t += 256) sx[t>>7][t&127] = Xa[p0*128 + t] - Xb[p0*128 + t];
    __syncthreads();
    int cg = tid & 31, pg = tid >> 5, c0 = cg*4;
    float a[2][4] = {{0,0,0,0},{0,0,0,0}};
    for (int j=0;j<128;j++){
        float xa = sx[pg][j], xb = sx[pg+8][j];
        float4 w4 = *(const float4*)&WT[j*128 + c0];
        const float* wp = &w4.x;
#pragma unroll
        for (int ci=0;ci<4;ci++){ a[0][ci] += wp[ci]*xa; a[1][ci] += wp[ci]*xb; }
    }
    float4 bv = *(const float4*)&bias[c0];
    const float* bp = &bv.x;
#pragma unroll
    for (int pp=0;pp<2;pp++){
        int p = p0 + pg + pp*8;
        *(float4*)&Y[p*128+c0] = make_float4(a[pp][0]+bp[0], a[pp][1]+bp[1], a[pp][2]+bp[2], a[pp][3]+bp[3]);
    }
}

// l5: xv = sa_v @ sres + b ; xqk = sa_qk @ sres
__global__ __launch_bounds__(256) void l5_kernel(const float* X, const float* WvT, const float* vb,
                                                 const float* WqkT, float* Yv, float* Yqk){
    __shared__ float sx[16][128];
    int tid = threadIdx.x;
    int p0 = blockIdx.x * 16;
    for (int t = tid; t < 2048; t += 256) sx[t>>7][t&127] = X[p0*128 + t];
    __syncthreads();
    int cg = tid & 31, pg = tid >> 5, c0 = cg*4;
    {
        float a[2][4] = {{0,0,0,0},{0,0,0,0}};
        for (int j=0;j<128;j++){
            float xa = sx[pg][j], xb = sx[pg+8][j];
            float4 w4 = *(const float4*)&WvT[j*128 + c0];
            const float* wp = &w4.x;
#pragma unroll
            for (int ci=0;ci<4;ci++){ a[0][ci] += wp[ci]*xa; a[1][ci] += wp[ci]*xb; }
        }
        float4 bv = *(const float4*)&vb[c0];
        const float* bp = &bv.x;
#pragma unroll
        for (int pp=0;pp<2;pp++){
            int p = p0 + pg + pp*8;
            *(float4*)&Yv[p*128+c0] = make_float4(a[pp][0]+bp[0], a[pp][1]+bp[1], a[pp][2]+bp[2], a[pp][3]+bp[3]);
        }
    }
    if (cg < 8){
        int cq = cg*4;
        float a[2][4] = {{0,0,0,0},{0,0,0,0}};
        for (int j=0;j<128;j++){
            float xa = sx[pg][j], xb = sx[pg+8][j];
            float4 w4 = *(const float4*)&WqkT[j*32 + cq];
            const float* wp = &w4.x;
#pragma unroll
            for (int ci=0;ci<4;ci++){ a[0][ci] += wp[ci]*xa; a[1][ci] += wp[ci]*xb; }
        }
#pragma unroll
        for (int pp=0;pp<2;pp++){
            int p = p0 + pg + pp*8;
            *(float4*)&Yqk[p*32+cq] = make_float4(a[pp][0], a[pp][1], a[pp][2], a[pp][3]);
        }
    }
}

// ---------------- batchnorm ----------------
__global__ void bn_stats_kernel(const float* X, float* sums){
    int tid = threadIdx.x;
    int c = tid & 127, half = tid >> 7;
    int r0 = blockIdx.x*128 + half*64;
    float s = 0.f, sq = 0.f;
    for (int r = r0; r < r0+64; r++){
        float v = X[r*128 + c];
        s += v; sq += v*v;
    }
    atomicAdd(&sums[c], s);
    atomicAdd(&sums[128+c], sq);
}

__global__ void bn1_apply_kernel(const float* res2, const float* x1, const float* sums,
                                 const float* g, const float* beta, float* sres){
    int gid = blockIdx.x*256 + threadIdx.x;
    int c = gid & 127;
    float mu = sums[c] * (1.0f/16384.f);
    float var = sums[128+c] * (1.0f/16384.f) - mu*mu;
    float inv = 1.0f / sqrtf(var + 1e-5f);
    float y = g[c]*(res2[gid]-mu)*inv + beta[c];
    sres[gid] = fmaxf(y, 0.f) + x1[gid];
}

__global__ void final_kernel(const float* sres, const float* xr2, const float* sums,
                             const float* g, const float* beta, float* out0){
    int gid = blockIdx.x*256 + threadIdx.x;
    int c = gid & 127;
    float mu = sums[c] * (1.0f/16384.f);
    float var = sums[128+c] * (1.0f/16384.f) - mu*mu;
    float inv = 1.0f / sqrtf(var + 1e-5f);
    float y = g[c]*(xr2[gid]-mu)*inv + beta[c];
    out0[gid] = sres[gid] + fmaxf(y, 0.f);
}

// ---------------- SA softmax row stats (2-pass recompute) ----------------
__global__ __launch_bounds__(256) void rowstats_kernel(const float* xqk, float* rm, float* rs){
    __shared__ float sxj[256][33];
    int tid = threadIdx.x;
    int b = blockIdx.x >> 8;
    int i0 = (blockIdx.x & 255) * 8;
    int ip = tid >> 6, l = tid & 63;
    const float* base = xqk + b*2048*32;
    float xi0[32], xi1[32];
#pragma unroll
    for (int c=0;c<32;c++){ xi0[c] = base[(i0+2*ip)*32+c]; xi1[c] = base[(i0+2*ip+1)*32+c]; }
    float m0 = -3e38f, m1 = -3e38f;
    for (int jc=0;jc<8;jc++){
        __syncthreads();
        for (int t=tid;t<8192;t+=256) sxj[t>>5][t&31] = base[jc*8192 + t];
        __syncthreads();
        for (int s=0;s<4;s++){
            int j = l + s*64;
            float d0=0.f, d1=0.f;
#pragma unroll
            for (int c=0;c<32;c++){ float xv = sxj[j][c]; d0 += xi0[c]*xv; d1 += xi1[c]*xv; }
            m0 = fmaxf(m0, d0); m1 = fmaxf(m1, d1);
        }
    }
#pragma unroll
    for (int mk=32; mk>=1; mk>>=1){ m0 = fmaxf(m0, __shfl_xor(m0,mk)); m1 = fmaxf(m1, __shfl_xor(m1,mk)); }
    float s0 = 0.f, s1 = 0.f;
    for (int jc=0;jc<8;jc++){
        __syncthreads();
        for (int t=tid;t<8192;t+=256) sxj[t>>5][t&31] = base[jc*8192 + t];
        __syncthreads();
        for (int s=0;s<4;s++){
            int j = l + s*64;
            float d0=0.f, d1=0.f;
#pragma unroll
            for (int c=0;c<32;c++){ float xv = sxj[j][c]; d0 += xi0[c]*xv; d1 += xi1[c]*xv; }
            s0 += expf(d0 - m0); s1 += expf(d1 - m1);
        }
    }
#pragma unroll
    for (int mk=32; mk>=1; mk>>=1){ s0 += __shfl_xor(s0,mk); s1 += __shfl_xor(s1,mk); }
    if (l == 0){
        rm[b*2048+i0+2*ip]   = m0; rs[b*2048+i0+2*ip]   = s0;
        rm[b*2048+i0+2*ip+1] = m1; rs[b*2048+i0+2*ip+1] = s1;
    }
}

__global__ __launch_bounds__(256) void colsum_kernel(const float* xqk, const float* rm, const float* rs, float* cs){
    __shared__ float sxi[256][33];
    __shared__ float srm[256], sirs[256];
    int tid = threadIdx.x;
    int blk = blockIdx.x;                 // 8b * 8jt * 8ic = 512
    int b = blk >> 6, jt = (blk>>3)&7, ic = blk&7;
    const float* base = xqk + b*2048*32;
    int j = jt*256 + tid;
    float xj[32];
#pragma unroll
    for (int c=0;c<32;c++) xj[c] = base[j*32+c];
    int i0 = ic*256;
    for (int t=tid;t<8192;t+=256) sxi[t>>5][t&31] = base[i0*32 + t];
    srm[tid] = rm[b*2048 + i0 + tid];
    sirs[tid] = 1.0f / rs[b*2048 + i0 + tid];
    __syncthreads();
    float acc = 0.f;
    for (int i=0;i<256;i++){
        float d = 0.f;
#pragma unroll
        for (int c=0;c<32;c++) d += sxi[i][c]*xj[c];
        acc += expf(d - srm[i]) * sirs[i];
    }
    atomicAdd(&cs[b*2048 + j], acc);
}

// xr[m][c] = (sum_n att[n][m] * xv[n][c]) / (1e-9 + colsum[m]),  att recomputed on the fly
__global__ __launch_bounds__(256) void xr_kernel(const float* xqk, const float* xv, const float* rm,
                                                 const float* rs, const float* cs, float* xr){
    __shared__ float sqm[32][33];
    __shared__ float sqn[64][33];
    __shared__ float sxv[64][128];
    __shared__ float satt[64][32];
    __shared__ float srm[64], sirs[64], sics[32];
    int tid = threadIdx.x;
    int b = blockIdx.x >> 6, mt = blockIdx.x & 63;
    const float* qb = xqk + b*2048*32;
    for (int t=tid; t<1024; t+=256) sqm[t>>5][t&31] = qb[(mt*32)*32 + t];
    if (tid < 32) sics[tid] = 1.0f / (1e-9f + cs[b*2048 + mt*32 + tid]);
    float acc[4][4];
#pragma unroll
    for (int i=0;i<4;i++)
#pragma unroll
        for (int jj=0;jj<4;jj++) acc[i][jj] = 0.f;
    int mg = tid >> 5, cgx = tid & 31, m0 = mg*4, c0 = cgx*4;
    int nq = tid >> 2, mq = tid & 3;
    for (int nc=0; nc<32; nc++){
        int n0 = nc*64;
        __syncthreads();
        for (int t=tid; t<2048; t+=256) sqn[t>>5][t&31] = qb[n0*32 + t];
        for (int t=tid; t<2048; t+=256){
            int r = t>>5, cq = (t&31)*4;
            *(float4*)&sxv[r][cq] = *(const float4*)&xv[(size_t)(b*2048+n0+r)*128 + cq];
        }
        if (tid < 64){ srm[tid] = rm[b*2048+n0+tid]; sirs[tid] = 1.0f/rs[b*2048+n0+tid]; }
        __syncthreads();
        {
            float qn[32];
#pragma unroll
            for (int c=0;c<32;c++) qn[c] = sqn[nq][c];
            float rmv = srm[nq], irsv = sirs[nq];
            float av[8];
#pragma unroll
            for (int mi=0;mi<8;mi++){
                int m = mq*8+mi;
                float d = 0.f;
#pragma unroll
                for (int c=0;c<32;c++) d += qn[c]*sqm[m][c];
                av[mi] = expf(d - rmv) * irsv;
            }
            *(float4*)&satt[nq][mq*8]   = make_float4(av[0],av[1],av[2],av[3]);
            *(float4*)&satt[nq][mq*8+4] = make_float4(av[4],av[5],av[6],av[7]);
        }
        __syncthreads();
        for (int nn=0; nn<64; nn++){
            float4 a4 = *(const float4*)&satt[nn][m0];
            float4 x4 = *(const float4*)&sxv[nn][c0];
            const float* ap = &a4.x; const float* xp = &x4.x;
#pragma unroll
            for (int mi=0;mi<4;mi++)
#pragma unroll
                for (int ci=0;ci<4;ci++) acc[mi][ci] += ap[mi]*xp[ci];
        }
    }
#pragma unroll
    for (int mi=0;mi<4;mi++){
        float sc = sics[m0+mi];
        *(float4*)&xr[(size_t)(b*2048 + mt*32 + m0+mi)*128 + c0] =
            make_float4(acc[mi][0]*sc, acc[mi][1]*sc, acc[mi][2]*sc, acc[mi][3]*sc);
    }
}

// ---------------- launch ----------------
extern "C" void kernel_launch(void* const* d_in, const int* in_sizes, int n_in,
                              void* d_out, int out_size, void* d_ws, size_t ws_size,
                              hipStream_t stream){
    (void)in_sizes; (void)n_in; (void)out_size; (void)ws_size;
    const float* feat = (const float*)d_in[0];
    const float* fc1w = (const float*)d_in[1];  const float* fc1b = (const float*)d_in[2];
    const float* fc2w = (const float*)d_in[3];  const float* fc2b = (const float*)d_in[4];
    const float* bng  = (const float*)d_in[5];  const float* bnb  = (const float*)d_in[6];
    const float* fb1w = (const float*)d_in[7];  const float* fb1b = (const float*)d_in[8];
    const float* fb2w = (const float*)d_in[9];  const float* fb2b = (const float*)d_in[10];
    const float* fg1w = (const float*)d_in[11]; const float* fg1b = (const float*)d_in[12];
    const float* fg2w = (const float*)d_in[13]; const float* fg2b = (const float*)d_in[14];
    const float* wq   = (const float*)d_in[15]; const float* wk   = (const float*)d_in[16];
    const float* wv   = (const float*)d_in[17];
    const float* saqk = (const float*)d_in[18];
    const float* savw = (const float*)d_in[19]; const float* savb = (const float*)d_in[20];
    const float* satw = (const float*)d_in[21]; const float* satb = (const float*)d_in[22];
    const float* sabng= (const float*)d_in[23]; const float* sabnb= (const float*)d_in[24];

    float* out0 = (float*)d_out;
    float* out1 = out0 + 2097152;

    char* ws = (char*)d_ws;
    size_t off = 0;
    auto A = [&](size_t bytes)->char*{
        char* r = ws + off;
        off = (off + bytes + 255) & ~(size_t)255;
        return r;
    };
    const size_t PBUF = (size_t)NPTS*128*4;   // 8 MB
    int*      g_idx  = (int*)A((size_t)NPTS*KNN*4);
    float*    g_x1   = (float*)A(PBUF);
    float*    g_q    = (float*)A(PBUF);
    float*    g_k1   = (float*)A(PBUF);
    float*    g_v1   = (float*)A(PBUF);
    float*    g_res  = (float*)A(PBUF);
    float*    g_res2 = (float*)A(PBUF);
    float*    g_sres = (float*)A(PBUF);
    float*    g_xv   = (float*)A(PBUF);
    float*    g_xr   = (float*)A(PBUF);
    float*    g_xr2  = (float*)A(PBUF);
    float*    g_xqk  = (float*)A((size_t)NPTS*32*4);
    float*    g_rm   = (float*)A((size_t)NPTS*4);
    float*    g_rs   = (float*)A((size_t)NPTS*4);
    float*    g_stats= (float*)A((size_t)(256+256+NPTS)*4);  // bn1(256) bn2(256) colsum(16384)
    float*    g_fb2T = (float*)A(65536);
    float*    g_fg1T = (float*)A(65536);
    float*    g_fg2T = (float*)A(65536);
    float*    g_wqT  = (float*)A(65536);
    float*    g_wkT  = (float*)A(65536);
    float*    g_wvT  = (float*)A(65536);
    float*    g_fc2T = (float*)A(65536);
    float*    g_savT = (float*)A(65536);
    float*    g_satT = (float*)A(65536);
    float*    g_sqkT = (float*)A(16384);

    float* bn1s = g_stats;
    float* bn2s = g_stats + 256;
    float* g_cs = g_stats + 512;

    hipMemsetAsync(g_stats, 0, (size_t)(256+256+NPTS)*4, stream);

    transpose_kernel<<<64, 256, 0, stream>>>(fb2w, g_fb2T, 128);
    transpose_kernel<<<64, 256, 0, stream>>>(fg1w, g_fg1T, 128);
    transpose_kernel<<<64, 256, 0, stream>>>(fg2w, g_fg2T, 128);
    transpose_kernel<<<64, 256, 0, stream>>>(wq,   g_wqT, 128);
    transpose_kernel<<<64, 256, 0, stream>>>(wk,   g_wkT, 128);
    transpose_kernel<<<64, 256, 0, stream>>>(wv,   g_wvT, 128);
    transpose_kernel<<<64, 256, 0, stream>>>(fc2w, g_fc2T, 128);
    transpose_kernel<<<64, 256, 0, stream>>>(savw, g_savT, 128);
    transpose_kernel<<<64, 256, 0, stream>>>(satw, g_satT, 128);
    transpose_kernel<<<16, 256, 0, stream>>>(saqk, g_sqkT, 32);

    knn_kernel<<<256, 256, 0, stream>>>(feat, g_idx);
    x1_kernel<<<8192, 256, 0, stream>>>(feat, fc1w, fc1b, g_x1);
    qkv_kernel<<<1024, 256, 0, stream>>>(g_x1, g_wqT, g_wkT, g_wvT, g_q, g_k1, g_v1);
    attn_kernel<<<8192, 256, 0, stream>>>(feat, g_idx, g_q, g_k1, g_v1,
                                          g_fb2T, g_fg1T, g_fg2T,
                                          fb1w, fb1b, fb2b, fg1b, fg2b, out1, g_res);
    lin_kernel<<<1024, 256, 0, stream>>>(g_res, g_fc2T, fc2b, g_res2);
    bn_stats_kernel<<<128, 256, 0, stream>>>(g_res2, bn1s);
    bn1_apply_kernel<<<8192, 256, 0, stream>>>(g_res2, g_x1, bn1s, bng, bnb, g_sres);
    l5_kernel<<<1024, 256, 0, stream>>>(g_sres, g_savT, savb, g_sqkT, g_xv, g_xqk);
    rowstats_kernel<<<2048, 256, 0, stream>>>(g_xqk, g_rm, g_rs);
    colsum_kernel<<<512, 256, 0, stream>>>(g_xqk, g_rm, g_rs, g_cs);
    xr_kernel<<<512, 256, 0, stream>>>(g_xqk, g_xv, g_rm, g_rs, g_cs, g_xr);
    l6_kernel<<<1024, 256, 0, stream>>>(g_sres, g_xr, g_satT, satb, g_xr2);
    bn_stats_kernel<<<128, 256, 0, stream>>>(g_xr2, bn2s);
    final_kernel<<<8192, 256, 0, stream>>>(g_sres, g_xr2, bn2s, sabng, sabnb, out0);
}

// Round 3
// 1317.944 us; speedup vs baseline: 2.3588x; 1.2605x over previous
//
#include <hip/hip_runtime.h>

#define NPTS 16384   // B*N = 8*2048
#define NB 2048
#define KNN 20

typedef __attribute__((ext_vector_type(4))) float f32x4;
typedef __attribute__((ext_vector_type(8))) short short8;

union U4S8 { uint4 q; short8 s; };
union W4   { unsigned u[4]; short8 s; };

__device__ __forceinline__ unsigned bf16_rne(float v){
    unsigned u = __float_as_uint(v);
    return (u + 0x7fffu + ((u>>16)&1u)) >> 16;
}
// pack fp32 -> (hi bf16) | (lo bf16 << 16), hi+lo ~= v to ~2^-17 rel
__device__ __forceinline__ unsigned pack_hl(float v){
    unsigned hi = bf16_rne(v);
    float r = v - __uint_as_float(hi<<16);
    unsigned lo = bf16_rne(r);
    return hi | (lo<<16);
}

// transpose [C][128] -> [j][C]  (fp32), C = 128 or 32
__global__ void transpose_kernel(const float* in, float* out, int C){
    int gid = blockIdx.x*256 + threadIdx.x;
    if (gid >= 128*C) return;
    int j = gid / C, c = gid - j*C;
    out[gid] = in[c*128 + j];
}

// pack fb2/fg1/fg2 into MFMA B-fragment layout (bf16):
// out[m*16384 + ct*2048 + ks*512 + lane*8 + e] = bf16(W[c][j]),
//   c = ct*16 + (lane&15), j = ks*32 + (lane>>4)*8 + e
__global__ void pack_bfrag_kernel(const float* w0, const float* w1, const float* w2, unsigned short* out){
    int gid = blockIdx.x*256 + threadIdx.x;
    if (gid >= 3*16384) return;
    int m = gid >> 14, r = gid & 16383;
    const float* W = (m==0)?w0:(m==1)?w1:w2;
    int e = r & 7, lane = (r>>3) & 63, ks = (r>>9)&3, ct = r>>11;
    int c = ct*16 + (lane&15), j = ks*32 + (lane>>4)*8 + e;
    out[gid] = (unsigned short)bf16_rne(W[c*128 + j]);
}

// ---------------- kNN ----------------
__device__ __forceinline__ double dist2_of(int n, int j, const float* sx, const float* sy, const float* sz){
    j &= 2047;
    double dx = (double)sx[j] - (double)sx[n];
    double dy = (double)sy[j] - (double)sy[n];
    double dz = (double)sz[j] - (double)sz[n];
    return dx*dx + dy*dy + dz*dz;
}
__device__ __forceinline__ bool knn_better(float va, int ja, float vb, int jb, int n,
                                           const float* sx, const float* sy, const float* sz){
    if (va != vb) return va > vb;
    if (ja == jb) return false;
    double da = dist2_of(n, ja, sx, sy, sz);
    double db = dist2_of(n, jb, sx, sy, sz);
    if (da != db) return da < db;
    return ja < jb;
}

__global__ __launch_bounds__(256) void knn_kernel(const float* feat, int* g_idx){
    __shared__ float sx[2048], sy[2048], sz[2048];
    __shared__ float sval[256][20];
    __shared__ int   sidx[256][20];
    int tid = threadIdx.x;
    int p0 = blockIdx.x * 64;
    int b = p0 >> 11;
    const float* fb = feat + b*3*2048;
    for (int i = tid; i < 2048; i += 256){ sx[i]=fb[i]; sy[i]=fb[2048+i]; sz[i]=fb[4096+i]; }
    __syncthreads();
    int pl = tid & 63, chunk = tid >> 6;
    int n = (p0 + pl) & 2047;
    double xi = sx[n], yi = sy[n], zi = sz[n];
    float val[20]; int idx[20];
#pragma unroll
    for (int k=0;k<20;k++){ val[k] = -3e38f; idx[k] = 0x7fffffff; }
    for (int j = chunk*512; j < chunk*512 + 512; j++){
        double dx = (double)sx[j]-xi, dy = (double)sy[j]-yi, dz = (double)sz[j]-zi;
        double d2 = dx*dx + dy*dy + dz*dz;
        float vf = (float)(-d2);
        bool tie = false;
#pragma unroll
        for (int s=0;s<20;s++) tie |= (vf == val[s]);
        if (!tie){
            bool bs = vf > val[19];
#pragma unroll
            for (int s=19; s>=1; s--){
                bool bm = vf > val[s-1];
                float nv = bm ? val[s-1] : vf;
                int   ni = bm ? idx[s-1] : j;
                val[s] = bs ? nv : val[s];
                idx[s] = bs ? ni : idx[s];
                bs = bm;
            }
            val[0] = bs ? vf : val[0];
            idx[0] = bs ? j  : idx[0];
        } else {
            bool bs = knn_better(vf, j, val[19], idx[19], n, sx, sy, sz);
#pragma unroll
            for (int s=19; s>=1; s--){
                bool bm = knn_better(vf, j, val[s-1], idx[s-1], n, sx, sy, sz);
                float nv = bm ? val[s-1] : vf;
                int   ni = bm ? idx[s-1] : j;
                val[s] = bs ? nv : val[s];
                idx[s] = bs ? ni : idx[s];
                bs = bm;
            }
            val[0] = bs ? vf : val[0];
            idx[0] = bs ? j  : idx[0];
        }
    }
#pragma unroll
    for (int k=0;k<20;k++){ sval[tid][k] = val[k]; sidx[tid][k] = idx[k]; }
    __syncthreads();
    if (tid < 64){
        int nn = (p0 + tid) & 2047;
        int ptr[4] = {0,0,0,0};
        for (int kk=0; kk<20; kk++){
            float bv = 0.f; int bi = 0x7fffffff; int bc = -1;
#pragma unroll
            for (int c=0;c<4;c++){
                if (ptr[c] < 20){
                    int row = c*64 + tid;
                    float v = sval[row][ptr[c]]; int ix = sidx[row][ptr[c]];
                    if (bc < 0 || knn_better(v, ix, bv, bi, nn, sx, sy, sz)){ bv=v; bi=ix; bc=c; }
                }
            }
            ptr[bc]++;
            g_idx[(p0+tid)*20 + kk] = bi;
        }
    }
}

// ---------------- x1 = xt @ fc1.T + b ----------------
__global__ void x1_kernel(const float* feat, const float* w, const float* bias, float* x1){
    int gid = blockIdx.x*256 + threadIdx.x;
    int p = gid >> 7, c = gid & 127;
    int b = p >> 11, n = p & 2047;
    const float* fb = feat + b*6144 + n;
    float v = bias[c];
    v += w[c*3+0]*fb[0];
    v += w[c*3+1]*fb[2048];
    v += w[c*3+2]*fb[4096];
    x1[gid] = v;
}

// ---------------- q/k/v ----------------
__global__ __launch_bounds__(256) void qkv_kernel(const float* x1, const float* wqT, const float* wkT,
                                                  const float* wvT, float* q, float* k1, float* v1){
    __shared__ float sx[16][128];
    int tid = threadIdx.x;
    int p0 = blockIdx.x * 16;
    for (int t = tid; t < 2048; t += 256) sx[t>>7][t&127] = x1[p0*128 + t];
    __syncthreads();
    int cg = tid & 31, pg = tid >> 5, c0 = cg*4;
    float aq[2][4] = {{0,0,0,0},{0,0,0,0}};
    float ak[2][4] = {{0,0,0,0},{0,0,0,0}};
    float av[2][4] = {{0,0,0,0},{0,0,0,0}};
    for (int j=0;j<128;j++){
        float xa = sx[pg][j], xb = sx[pg+8][j];
        float4 wq4 = *(const float4*)&wqT[j*128 + c0];
        float4 wk4 = *(const float4*)&wkT[j*128 + c0];
        float4 wv4 = *(const float4*)&wvT[j*128 + c0];
        const float* wqp = &wq4.x; const float* wkp = &wk4.x; const float* wvp = &wv4.x;
#pragma unroll
        for (int ci=0; ci<4; ci++){
            aq[0][ci] += wqp[ci]*xa; aq[1][ci] += wqp[ci]*xb;
            ak[0][ci] += wkp[ci]*xa; ak[1][ci] += wkp[ci]*xb;
            av[0][ci] += wvp[ci]*xa; av[1][ci] += wvp[ci]*xb;
        }
    }
#pragma unroll
    for (int pp=0; pp<2; pp++){
        int p = p0 + pg + pp*8;
        *(float4*)&q [p*128 + c0] = make_float4(aq[pp][0],aq[pp][1],aq[pp][2],aq[pp][3]);
        *(float4*)&k1[p*128 + c0] = make_float4(ak[pp][0],ak[pp][1],ak[pp][2],ak[pp][3]);
        *(float4*)&v1[p*128 + c0] = make_float4(av[pp][0],av[pp][1],av[pp][2],av[pp][3]);
    }
}

// ---------------- fused MFMA edge/attention kernel ----------------
// 4 points/block (80 rows = 5 x 16-row MFMA tiles), 256 threads = 4 waves,
// wave w owns col-tiles {2w, 2w+1}. Activations: packed hi/lo bf16 in one LDS buffer.
__device__ __forceinline__ void stage_gemm(const unsigned* buf, const unsigned short* wb,
                                           int lane, int ct0, f32x4 acc[5][2]){
    short8 bf[2][4];
#pragma unroll
    for (int ci=0; ci<2; ci++)
#pragma unroll
    for (int ks=0; ks<4; ks++){
        U4S8 u; u.q = *(const uint4*)(wb + ((ct0+ci)*4 + ks)*512 + lane*8);
        bf[ci][ks] = u.s;
    }
#pragma unroll
    for (int rt=0; rt<5; rt++)
#pragma unroll
    for (int ci=0; ci<2; ci++)
        acc[rt][ci] = (f32x4){0.f,0.f,0.f,0.f};
    int abase = (lane&15)*132 + (lane>>4)*8;
#pragma unroll
    for (int rt=0; rt<5; rt++){
#pragma unroll
        for (int ks=0; ks<4; ks++){
            const unsigned* ap = buf + rt*16*132 + ks*32 + abase;
            uint4 w0 = *(const uint4*)ap;
            uint4 w1 = *(const uint4*)(ap+4);
            W4 hi, lo;
            hi.u[0] = __builtin_amdgcn_perm(w0.y, w0.x, 0x05040100u);
            lo.u[0] = __builtin_amdgcn_perm(w0.y, w0.x, 0x07060302u);
            hi.u[1] = __builtin_amdgcn_perm(w0.w, w0.z, 0x05040100u);
            lo.u[1] = __builtin_amdgcn_perm(w0.w, w0.z, 0x07060302u);
            hi.u[2] = __builtin_amdgcn_perm(w1.y, w1.x, 0x05040100u);
            lo.u[2] = __builtin_amdgcn_perm(w1.y, w1.x, 0x07060302u);
            hi.u[3] = __builtin_amdgcn_perm(w1.w, w1.z, 0x05040100u);
            lo.u[3] = __builtin_amdgcn_perm(w1.w, w1.z, 0x07060302u);
#pragma unroll
            for (int ci=0; ci<2; ci++){
                acc[rt][ci] = __builtin_amdgcn_mfma_f32_16x16x32_bf16(hi.s, bf[ci][ks], acc[rt][ci], 0,0,0);
                acc[rt][ci] = __builtin_amdgcn_mfma_f32_16x16x32_bf16(lo.s, bf[ci][ks], acc[rt][ci], 0,0,0);
            }
        }
    }
}

__global__ __launch_bounds__(256, 3) void attn_kernel(
        const float* feat, const int* g_idx, const float* g_q, const float* g_k1, const float* g_v1,
        const unsigned short* wpk,     // fb2(0), fg1(+16384), fg2(+32768) B-frag packed
        const float* fb1w, const float* fb1b, const float* fb2b, const float* fg1b, const float* fg2b,
        float* g_attn, float* g_res){
    __shared__ __align__(16) unsigned buf[80*132];   // 42240 B
    __shared__ float sh_q[512];
    __shared__ float sh_e[80*6];
    __shared__ int   sh_ix[80];
    int tid = threadIdx.x;
    int lane = tid & 63, wave = tid >> 6;
    int gp0 = blockIdx.x * 4;
    int b = gp0 >> 11;
    size_t kvbase = (size_t)b*2048*128;

    sh_q[tid]     = g_q[gp0*128 + tid];
    sh_q[tid+256] = g_q[gp0*128 + tid + 256];
    if (tid < 80){
        int r = tid;
        int nb = g_idx[gp0*20 + r];
        sh_ix[r] = nb;
        int p = (r*205) >> 12;           // r/20 for r<80
        int n = (gp0 & 2047) + p;
        const float* fbp = feat + b*6144;
        float cx = fbp[n], cy = fbp[2048+n], cz = fbp[4096+n];
        float nx = fbp[nb], ny = fbp[2048+nb], nz = fbp[4096+nb];
        sh_e[r*6+0] = nx-cx; sh_e[r*6+1] = ny-cy; sh_e[r*6+2] = nz-cz;
        sh_e[r*6+3] = cx;    sh_e[r*6+4] = cy;    sh_e[r*6+5] = cz;
    }
    __syncthreads();

    // P1: h = relu(fb1 . e + b1)  -> buf (packed)
    {
        int c = tid & 127, rh = tid >> 7;
        float w0=fb1w[c*6+0], w1=fb1w[c*6+1], w2=fb1w[c*6+2], w3=fb1w[c*6+3], w4=fb1w[c*6+4], w5=fb1w[c*6+5];
        float bb = fb1b[c];
#pragma unroll
        for (int rr=0; rr<40; rr++){
            int r = rr*2 + rh;
            const float* e = &sh_e[r*6];
            float v = bb + w0*e[0]+w1*e[1]+w2*e[2]+w3*e[3]+w4*e[4]+w5*e[5];
            buf[r*132 + c] = pack_hl(fmaxf(v, 0.f));
        }
    }
    __syncthreads();

    int ct0 = wave*2;
    int colA = ct0*16 + (lane&15);
    int colB = colA + 16;
    int quad = lane >> 4;
    f32x4 acc[5][2];

    // ---- P2: kf = fb2.h + b2 ; a_in = q - kg + kf ----
    stage_gemm(buf, wpk, lane, ct0, acc);
    {
        float bA = fb2b[colA], bB = fb2b[colB];
#pragma unroll
        for (int rt=0; rt<5; rt++)
#pragma unroll
        for (int ci=0; ci<2; ci++){
            int col = ci ? colB : colA;
            float bias = ci ? bB : bA;
#pragma unroll
            for (int reg=0; reg<4; reg++){
                int row = rt*16 + quad*4 + reg;
                float kf = acc[rt][ci][reg] + bias;
                g_attn[(size_t)(gp0*20 + row)*128 + col] = kf;   // kf scratch in out1
                int p = (row*205)>>12;
                int nb = sh_ix[row];
                float kg = g_k1[kvbase + (size_t)nb*128 + col];
                float ain = sh_q[p*128 + col] - kg + kf;
                acc[rt][ci][reg] = __uint_as_float(pack_hl(ain));
            }
        }
    }
    __syncthreads();
#pragma unroll
    for (int rt=0; rt<5; rt++)
#pragma unroll
    for (int ci=0; ci<2; ci++)
#pragma unroll
    for (int reg=0; reg<4; reg++){
        int row = rt*16 + quad*4 + reg;
        int col = ci ? colB : colA;
        buf[row*132 + col] = __float_as_uint(acc[rt][ci][reg]);
    }
    __syncthreads();

    // ---- P3: t = relu(fg1 . a_in + b) ----
    stage_gemm(buf, wpk + 16384, lane, ct0, acc);
    {
        float bA = fg1b[colA], bB = fg1b[colB];
#pragma unroll
        for (int rt=0; rt<5; rt++)
#pragma unroll
        for (int ci=0; ci<2; ci++){
            float bias = ci ? bB : bA;
#pragma unroll
            for (int reg=0; reg<4; reg++)
                acc[rt][ci][reg] = __uint_as_float(pack_hl(fmaxf(acc[rt][ci][reg] + bias, 0.f)));
        }
    }
    __syncthreads();
#pragma unroll
    for (int rt=0; rt<5; rt++)
#pragma unroll
    for (int ci=0; ci<2; ci++)
#pragma unroll
    for (int reg=0; reg<4; reg++){
        int row = rt*16 + quad*4 + reg;
        int col = ci ? colB : colA;
        buf[row*132 + col] = __float_as_uint(acc[rt][ci][reg]);
    }
    __syncthreads();

    // ---- P4: a2 = fg2 . t + b  (stored fp32 in buf) ----
    stage_gemm(buf, wpk + 32768, lane, ct0, acc);
    {
        float bA = fg2b[colA], bB = fg2b[colB];
#pragma unroll
        for (int rt=0; rt<5; rt++)
#pragma unroll
        for (int ci=0; ci<2; ci++){
            float bias = ci ? bB : bA;
#pragma unroll
            for (int reg=0; reg<4; reg++)
                acc[rt][ci][reg] += bias;
        }
    }
    __syncthreads();
#pragma unroll
    for (int rt=0; rt<5; rt++)
#pragma unroll
    for (int ci=0; ci<2; ci++)
#pragma unroll
    for (int reg=0; reg<4; reg++){
        int row = rt*16 + quad*4 + reg;
        int col = ci ? colB : colA;
        buf[row*132 + col] = __float_as_uint(acc[rt][ci][reg]);
    }
    __syncthreads();

    // ---- P5: log_softmax over K + attn write + res ----
#pragma unroll
    for (int w=0; w<2; w++){
        int wk = tid + 256*w;          // 0..511
        int p = wk >> 7, c = wk & 127;
        float s[20];
        float m = -3e38f;
#pragma unroll
        for (int k=0;k<20;k++){
            s[k] = __uint_as_float(buf[(p*20+k)*132 + c]) * 0.08838834764831845f;
            m = fmaxf(m, s[k]);
        }
        float sum = 0.f;
#pragma unroll
        for (int k=0;k<20;k++) sum += expf(s[k] - m);
        float L = m + logf(sum);
        float* op = g_attn + (size_t)(gp0+p)*20*128 + c;
        float res = 0.f;
#pragma unroll
        for (int k=0;k<20;k++){
            float at = s[k] - L;
            float kf = op[k*128];                 // read kf scratch first
            int nb = sh_ix[p*20+k];
            float vv = g_v1[kvbase + (size_t)nb*128 + c];
            res += at * (vv + kf);
            op[k*128] = at;                       // then overwrite with attn
        }
        g_res[(gp0+p)*128 + c] = res;
    }
}

// ---------------- generic per-point linear (128->128) ----------------
__global__ __launch_bounds__(256) void lin_kernel(const float* X, const float* WT, const float* bias, float* Y){
    __shared__ float sx[16][128];
    int tid = threadIdx.x;
    int p0 = blockIdx.x * 16;
    for (int t = tid; t < 2048; t += 256) sx[t>>7][t&127] = X[p0*128 + t];
    __syncthreads();
    int cg = tid & 31, pg = tid >> 5, c0 = cg*4;
    float a[2][4] = {{0,0,0,0},{0,0,0,0}};
    for (int j=0;j<128;j++){
        float xa = sx[pg][j], xb = sx[pg+8][j];
        float4 w4 = *(const float4*)&WT[j*128 + c0];
        const float* wp = &w4.x;
#pragma unroll
        for (int ci=0;ci<4;ci++){ a[0][ci] += wp[ci]*xa; a[1][ci] += wp[ci]*xb; }
    }
    float4 bv = *(const float4*)&bias[c0];
    const float* bp = &bv.x;
#pragma unroll
    for (int pp=0;pp<2;pp++){
        int p = p0 + pg + pp*8;
        *(float4*)&Y[p*128+c0] = make_float4(a[pp][0]+bp[0], a[pp][1]+bp[1], a[pp][2]+bp[2], a[pp][3]+bp[3]);
    }
}

__global__ __launch_bounds__(256) void l6_kernel(const float* Xa, const float* Xb, const float* WT,
                                                 const float* bias, float* Y){
    __shared__ float sx[16][128];
    int tid = threadIdx.x;
    int p0 = blockIdx.x * 16;
    for (int t = tid; t < 2048; t += 256) sx[t>>7][t&127] = Xa[p0*128 + t] - Xb[p0*128 + t];
    __syncthreads();
    int cg = tid & 31, pg = tid >> 5, c0 = cg*4;
    float a[2][4] = {{0,0,0,0},{0,0,0,0}};
    for (int j=0;j<128;j++){
        float xa = sx[pg][j], xb = sx[pg+8][j];
        float4 w4 = *(const float4*)&WT[j*128 + c0];
        const float* wp = &w4.x;
#pragma unroll
        for (int ci=0;ci<4;ci++){ a[0][ci] += wp[ci]*xa; a[1][ci] += wp[ci]*xb; }
    }
    float4 bv = *(const float4*)&bias[c0];
    const float* bp = &bv.x;
#pragma unroll
    for (int pp=0;pp<2;pp++){
        int p = p0 + pg + pp*8;
        *(float4*)&Y[p*128+c0] = make_float4(a[pp][0]+bp[0], a[pp][1]+bp[1], a[pp][2]+bp[2], a[pp][3]+bp[3]);
    }
}

__global__ __launch_bounds__(256) void l5_kernel(const float* X, const float* WvT, const float* vb,
                                                 const float* WqkT, float* Yv, float* Yqk){
    __shared__ float sx[16][128];
    int tid = threadIdx.x;
    int p0 = blockIdx.x * 16;
    for (int t = tid; t < 2048; t += 256) sx[t>>7][t&127] = X[p0*128 + t];
    __syncthreads();
    int cg = tid & 31, pg = tid >> 5, c0 = cg*4;
    {
        float a[2][4] = {{0,0,0,0},{0,0,0,0}};
        for (int j=0;j<128;j++){
            float xa = sx[pg][j], xb = sx[pg+8][j];
            float4 w4 = *(const float4*)&WvT[j*128 + c0];
            const float* wp = &w4.x;
#pragma unroll
            for (int ci=0;ci<4;ci++){ a[0][ci] += wp[ci]*xa; a[1][ci] += wp[ci]*xb; }
        }
        float4 bv = *(const float4*)&vb[c0];
        const float* bp = &bv.x;
#pragma unroll
        for (int pp=0;pp<2;pp++){
            int p = p0 + pg + pp*8;
            *(float4*)&Yv[p*128+c0] = make_float4(a[pp][0]+bp[0], a[pp][1]+bp[1], a[pp][2]+bp[2], a[pp][3]+bp[3]);
        }
    }
    if (cg < 8){
        int cq = cg*4;
        float a[2][4] = {{0,0,0,0},{0,0,0,0}};
        for (int j=0;j<128;j++){
            float xa = sx[pg][j], xb = sx[pg+8][j];
            float4 w4 = *(const float4*)&WqkT[j*32 + cq];
            const float* wp = &w4.x;
#pragma unroll
            for (int ci=0;ci<4;ci++){ a[0][ci] += wp[ci]*xa; a[1][ci] += wp[ci]*xb; }
        }
#pragma unroll
        for (int pp=0;pp<2;pp++){
            int p = p0 + pg + pp*8;
            *(float4*)&Yqk[p*32+cq] = make_float4(a[pp][0], a[pp][1], a[pp][2], a[pp][3]);
        }
    }
}

// ---------------- batchnorm ----------------
__global__ void bn_stats_kernel(const float* X, float* sums){
    int tid = threadIdx.x;
    int c = tid & 127, half = tid >> 7;
    int r0 = blockIdx.x*128 + half*64;
    float s = 0.f, sq = 0.f;
    for (int r = r0; r < r0+64; r++){
        float v = X[r*128 + c];
        s += v; sq += v*v;
    }
    atomicAdd(&sums[c], s);
    atomicAdd(&sums[128+c], sq);
}

__global__ void bn1_apply_kernel(const float* res2, const float* x1, const float* sums,
                                 const float* g, const float* beta, float* sres){
    int gid = blockIdx.x*256 + threadIdx.x;
    int c = gid & 127;
    float mu = sums[c] * (1.0f/16384.f);
    float var = sums[128+c] * (1.0f/16384.f) - mu*mu;
    float inv = 1.0f / sqrtf(var + 1e-5f);
    float y = g[c]*(res2[gid]-mu)*inv + beta[c];
    sres[gid] = fmaxf(y, 0.f) + x1[gid];
}

__global__ void final_kernel(const float* sres, const float* xr2, const float* sums,
                             const float* g, const float* beta, float* out0){
    int gid = blockIdx.x*256 + threadIdx.x;
    int c = gid & 127;
    float mu = sums[c] * (1.0f/16384.f);
    float var = sums[128+c] * (1.0f/16384.f) - mu*mu;
    float inv = 1.0f / sqrtf(var + 1e-5f);
    float y = g[c]*(xr2[gid]-mu)*inv + beta[c];
    out0[gid] = sres[gid] + fmaxf(y, 0.f);
}

// ---------------- SA softmax row stats (2-pass recompute) ----------------
__global__ __launch_bounds__(256) void rowstats_kernel(const float* xqk, float* rm, float* rs){
    __shared__ float sxj[256][33];
    int tid = threadIdx.x;
    int b = blockIdx.x >> 8;
    int i0 = (blockIdx.x & 255) * 8;
    int ip = tid >> 6, l = tid & 63;
    const float* base = xqk + b*2048*32;
    float xi0[32], xi1[32];
#pragma unroll
    for (int c=0;c<32;c++){ xi0[c] = base[(i0+2*ip)*32+c]; xi1[c] = base[(i0+2*ip+1)*32+c]; }
    float m0 = -3e38f, m1 = -3e38f;
    for (int jc=0;jc<8;jc++){
        __syncthreads();
        for (int t=tid;t<8192;t+=256) sxj[t>>5][t&31] = base[jc*8192 + t];
        __syncthreads();
        for (int s=0;s<4;s++){
            int j = l + s*64;
            float d0=0.f, d1=0.f;
#pragma unroll
            for (int c=0;c<32;c++){ float xv = sxj[j][c]; d0 += xi0[c]*xv; d1 += xi1[c]*xv; }
            m0 = fmaxf(m0, d0); m1 = fmaxf(m1, d1);
        }
    }
#pragma unroll
    for (int mk=32; mk>=1; mk>>=1){ m0 = fmaxf(m0, __shfl_xor(m0,mk)); m1 = fmaxf(m1, __shfl_xor(m1,mk)); }
    float s0 = 0.f, s1 = 0.f;
    for (int jc=0;jc<8;jc++){
        __syncthreads();
        for (int t=tid;t<8192;t+=256) sxj[t>>5][t&31] = base[jc*8192 + t];
        __syncthreads();
        for (int s=0;s<4;s++){
            int j = l + s*64;
            float d0=0.f, d1=0.f;
#pragma unroll
            for (int c=0;c<32;c++){ float xv = sxj[j][c]; d0 += xi0[c]*xv; d1 += xi1[c]*xv; }
            s0 += expf(d0 - m0); s1 += expf(d1 - m1);
        }
    }
#pragma unroll
    for (int mk=32; mk>=1; mk>>=1){ s0 += __shfl_xor(s0,mk); s1 += __shfl_xor(s1,mk); }
    if (l == 0){
        rm[b*2048+i0+2*ip]   = m0; rs[b*2048+i0+2*ip]   = s0;
        rm[b*2048+i0+2*ip+1] = m1; rs[b*2048+i0+2*ip+1] = s1;
    }
}

__global__ __launch_bounds__(256) void colsum_kernel(const float* xqk, const float* rm, const float* rs, float* cs){
    __shared__ float sxi[256][33];
    __shared__ float srm[256], sirs[256];
    int tid = threadIdx.x;
    int blk = blockIdx.x;
    int b = blk >> 6, jt = (blk>>3)&7, ic = blk&7;
    const float* base = xqk + b*2048*32;
    int j = jt*256 + tid;
    float xj[32];
#pragma unroll
    for (int c=0;c<32;c++) xj[c] = base[j*32+c];
    int i0 = ic*256;
    for (int t=tid;t<8192;t+=256) sxi[t>>5][t&31] = base[i0*32 + t];
    srm[tid] = rm[b*2048 + i0 + tid];
    sirs[tid] = 1.0f / rs[b*2048 + i0 + tid];
    __syncthreads();
    float acc = 0.f;
    for (int i=0;i<256;i++){
        float d = 0.f;
#pragma unroll
        for (int c=0;c<32;c++) d += sxi[i][c]*xj[c];
        acc += expf(d - srm[i]) * sirs[i];
    }
    atomicAdd(&cs[b*2048 + j], acc);
}

__global__ __launch_bounds__(256) void xr_kernel(const float* xqk, const float* xv, const float* rm,
                                                 const float* rs, const float* cs, float* xr){
    __shared__ float sqm[32][33];
    __shared__ float sqn[64][33];
    __shared__ float sxv[64][128];
    __shared__ float satt[64][32];
    __shared__ float srm[64], sirs[64], sics[32];
    int tid = threadIdx.x;
    int b = blockIdx.x >> 6, mt = blockIdx.x & 63;
    const float* qb = xqk + b*2048*32;
    for (int t=tid; t<1024; t+=256) sqm[t>>5][t&31] = qb[(mt*32)*32 + t];
    if (tid < 32) sics[tid] = 1.0f / (1e-9f + cs[b*2048 + mt*32 + tid]);
    float acc[4][4];
#pragma unroll
    for (int i=0;i<4;i++)
#pragma unroll
        for (int jj=0;jj<4;jj++) acc[i][jj] = 0.f;
    int mg = tid >> 5, cgx = tid & 31, m0 = mg*4, c0 = cgx*4;
    int nq = tid >> 2, mq = tid & 3;
    for (int nc=0; nc<32; nc++){
        int n0 = nc*64;
        __syncthreads();
        for (int t=tid; t<2048; t+=256) sqn[t>>5][t&31] = qb[n0*32 + t];
        for (int t=tid; t<2048; t+=256){
            int r = t>>5, cq = (t&31)*4;
            *(float4*)&sxv[r][cq] = *(const float4*)&xv[(size_t)(b*2048+n0+r)*128 + cq];
        }
        if (tid < 64){ srm[tid] = rm[b*2048+n0+tid]; sirs[tid] = 1.0f/rs[b*2048+n0+tid]; }
        __syncthreads();
        {
            float qn[32];
#pragma unroll
            for (int c=0;c<32;c++) qn[c] = sqn[nq][c];
            float rmv = srm[nq], irsv = sirs[nq];
            float av[8];
#pragma unroll
            for (int mi=0;mi<8;mi++){
                int m = mq*8+mi;
                float d = 0.f;
#pragma unroll
                for (int c=0;c<32;c++) d += qn[c]*sqm[m][c];
                av[mi] = expf(d - rmv) * irsv;
            }
            *(float4*)&satt[nq][mq*8]   = make_float4(av[0],av[1],av[2],av[3]);
            *(float4*)&satt[nq][mq*8+4] = make_float4(av[4],av[5],av[6],av[7]);
        }
        __syncthreads();
        for (int nn=0; nn<64; nn++){
            float4 a4 = *(const float4*)&satt[nn][m0];
            float4 x4 = *(const float4*)&sxv[nn][c0];
            const float* ap = &a4.x; const float* xp = &x4.x;
#pragma unroll
            for (int mi=0;mi<4;mi++)
#pragma unroll
                for (int ci=0;ci<4;ci++) acc[mi][ci] += ap[mi]*xp[ci];
        }
    }
#pragma unroll
    for (int mi=0;mi<4;mi++){
        float sc = sics[m0+mi];
        *(float4*)&xr[(size_t)(b*2048 + mt*32 + m0+mi)*128 + c0] =
            make_float4(acc[mi][0]*sc, acc[mi][1]*sc, acc[mi][2]*sc, acc[mi][3]*sc);
    }
}

// ---------------- launch ----------------
extern "C" void kernel_launch(void* const* d_in, const int* in_sizes, int n_in,
                              void* d_out, int out_size, void* d_ws, size_t ws_size,
                              hipStream_t stream){
    (void)in_sizes; (void)n_in; (void)out_size; (void)ws_size;
    const float* feat = (const float*)d_in[0];
    const float* fc1w = (const float*)d_in[1];  const float* fc1b = (const float*)d_in[2];
    const float* fc2w = (const float*)d_in[3];  const float* fc2b = (const float*)d_in[4];
    const float* bng  = (const float*)d_in[5];  const float* bnb  = (const float*)d_in[6];
    const float* fb1w = (const float*)d_in[7];  const float* fb1b = (const float*)d_in[8];
    const float* fb2w = (const float*)d_in[9];  const float* fb2b = (const float*)d_in[10];
    const float* fg1w = (const float*)d_in[11]; const float* fg1b = (const float*)d_in[12];
    const float* fg2w = (const float*)d_in[13]; const float* fg2b = (const float*)d_in[14];
    const float* wq   = (const float*)d_in[15]; const float* wk   = (const float*)d_in[16];
    const float* wv   = (const float*)d_in[17];
    const float* saqk = (const float*)d_in[18];
    const float* savw = (const float*)d_in[19]; const float* savb = (const float*)d_in[20];
    const float* satw = (const float*)d_in[21]; const float* satb = (const float*)d_in[22];
    const float* sabng= (const float*)d_in[23]; const float* sabnb= (const float*)d_in[24];

    float* out0 = (float*)d_out;
    float* out1 = out0 + 2097152;

    char* ws = (char*)d_ws;
    size_t off = 0;
    auto A = [&](size_t bytes)->char*{
        char* r = ws + off;
        off = (off + bytes + 255) & ~(size_t)255;
        return r;
    };
    const size_t PBUF = (size_t)NPTS*128*4;   // 8 MB
    int*      g_idx  = (int*)A((size_t)NPTS*KNN*4);
    float*    g_x1   = (float*)A(PBUF);
    float*    g_q    = (float*)A(PBUF);
    float*    g_k1   = (float*)A(PBUF);
    float*    g_v1   = (float*)A(PBUF);
    float*    g_res  = (float*)A(PBUF);
    float*    g_res2 = (float*)A(PBUF);
    float*    g_sres = (float*)A(PBUF);
    float*    g_xv   = (float*)A(PBUF);
    float*    g_xr   = (float*)A(PBUF);
    float*    g_xr2  = (float*)A(PBUF);
    float*    g_xqk  = (float*)A((size_t)NPTS*32*4);
    float*    g_rm   = (float*)A((size_t)NPTS*4);
    float*    g_rs   = (float*)A((size_t)NPTS*4);
    float*    g_stats= (float*)A((size_t)(256+256+NPTS)*4);
    unsigned short* g_wpk = (unsigned short*)A((size_t)3*16384*2);
    float*    g_wqT  = (float*)A(65536);
    float*    g_wkT  = (float*)A(65536);
    float*    g_wvT  = (float*)A(65536);
    float*    g_fc2T = (float*)A(65536);
    float*    g_savT = (float*)A(65536);
    float*    g_satT = (float*)A(65536);
    float*    g_sqkT = (float*)A(16384);

    float* bn1s = g_stats;
    float* bn2s = g_stats + 256;
    float* g_cs = g_stats + 512;

    hipMemsetAsync(g_stats, 0, (size_t)(256+256+NPTS)*4, stream);

    pack_bfrag_kernel<<<192, 256, 0, stream>>>(fb2w, fg1w, fg2w, g_wpk);
    transpose_kernel<<<64, 256, 0, stream>>>(wq,   g_wqT, 128);
    transpose_kernel<<<64, 256, 0, stream>>>(wk,   g_wkT, 128);
    transpose_kernel<<<64, 256, 0, stream>>>(wv,   g_wvT, 128);
    transpose_kernel<<<64, 256, 0, stream>>>(fc2w, g_fc2T, 128);
    transpose_kernel<<<64, 256, 0, stream>>>(savw, g_savT, 128);
    transpose_kernel<<<64, 256, 0, stream>>>(satw, g_satT, 128);
    transpose_kernel<<<16, 256, 0, stream>>>(saqk, g_sqkT, 32);

    knn_kernel<<<256, 256, 0, stream>>>(feat, g_idx);
    x1_kernel<<<8192, 256, 0, stream>>>(feat, fc1w, fc1b, g_x1);
    qkv_kernel<<<1024, 256, 0, stream>>>(g_x1, g_wqT, g_wkT, g_wvT, g_q, g_k1, g_v1);
    attn_kernel<<<4096, 256, 0, stream>>>(feat, g_idx, g_q, g_k1, g_v1, g_wpk,
                                          fb1w, fb1b, fb2b, fg1b, fg2b, out1, g_res);
    lin_kernel<<<1024, 256, 0, stream>>>(g_res, g_fc2T, fc2b, g_res2);
    bn_stats_kernel<<<128, 256, 0, stream>>>(g_res2, bn1s);
    bn1_apply_kernel<<<8192, 256, 0, stream>>>(g_res2, g_x1, bn1s, bng, bnb, g_sres);
    l5_kernel<<<1024, 256, 0, stream>>>(g_sres, g_savT, savb, g_sqkT, g_xv, g_xqk);
    rowstats_kernel<<<2048, 256, 0, stream>>>(g_xqk, g_rm, g_rs);
    colsum_kernel<<<512, 256, 0, stream>>>(g_xqk, g_rm, g_rs, g_cs);
    xr_kernel<<<512, 256, 0, stream>>>(g_xqk, g_xv, g_rm, g_rs, g_cs, g_xr);
    l6_kernel<<<1024, 256, 0, stream>>>(g_sres, g_xr, g_satT, satb, g_xr2);
    bn_stats_kernel<<<128, 256, 0, stream>>>(g_xr2, bn2s);
    final_kernel<<<8192, 256, 0, stream>>>(g_sres, g_xr2, bn2s, sabng, sabnb, out0);
}

// Round 4
// 1198.890 us; speedup vs baseline: 2.5931x; 1.0993x over previous
//
#include <hip/hip_runtime.h>

#define NPTS 16384   // B*N = 8*2048
#define NB 2048
#define KNN 20

typedef __attribute__((ext_vector_type(4))) float f32x4;
typedef __attribute__((ext_vector_type(8))) short short8;

union U4S8 { uint4 q; short8 s; };
union W4   { unsigned u[4]; short8 s; };

__device__ __forceinline__ unsigned bf16_rne(float v){
    unsigned u = __float_as_uint(v);
    return (u + 0x7fffu + ((u>>16)&1u)) >> 16;
}
// pack fp32 -> (hi bf16) | (lo bf16 << 16), hi+lo ~= v to ~2^-17 rel
__device__ __forceinline__ unsigned pack_hl(float v){
    unsigned hi = bf16_rne(v);
    float r = v - __uint_as_float(hi<<16);
    unsigned lo = bf16_rne(r);
    return hi | (lo<<16);
}

// transpose [C][128] -> [j][C]  (fp32), C = 128 or 32
__global__ void transpose_kernel(const float* in, float* out, int C){
    int gid = blockIdx.x*256 + threadIdx.x;
    if (gid >= 128*C) return;
    int j = gid / C, c = gid - j*C;
    out[gid] = in[c*128 + j];
}

// pack fb2/fg1/fg2 into MFMA B-fragment layout (bf16):
// out[m*16384 + ct*2048 + ks*512 + lane*8 + e] = bf16(W[c][j]),
//   c = ct*16 + (lane&15), j = ks*32 + (lane>>4)*8 + e
__global__ void pack_bfrag_kernel(const float* w0, const float* w1, const float* w2, unsigned short* out){
    int gid = blockIdx.x*256 + threadIdx.x;
    if (gid >= 3*16384) return;
    int m = gid >> 14, r = gid & 16383;
    const float* W = (m==0)?w0:(m==1)?w1:w2;
    int e = r & 7, lane = (r>>3) & 63, ks = (r>>9)&3, ct = r>>11;
    int c = ct*16 + (lane&15), j = ks*32 + (lane>>4)*8 + e;
    out[gid] = (unsigned short)bf16_rne(W[c*128 + j]);
}

// ---------------- kNN ----------------
__device__ __forceinline__ double dist2_of(int n, int j, const float* sx, const float* sy, const float* sz){
    j &= 2047;
    double dx = (double)sx[j] - (double)sx[n];
    double dy = (double)sy[j] - (double)sy[n];
    double dz = (double)sz[j] - (double)sz[n];
    return dx*dx + dy*dy + dz*dz;
}
__device__ __forceinline__ bool knn_better(float va, int ja, float vb, int jb, int n,
                                           const float* sx, const float* sy, const float* sz){
    if (va != vb) return va > vb;
    if (ja == jb) return false;
    double da = dist2_of(n, ja, sx, sy, sz);
    double db = dist2_of(n, jb, sx, sy, sz);
    if (da != db) return da < db;
    return ja < jb;
}

// 32 points/block, 512 blocks -> 2 blocks/CU (8 waves/CU) for latency hiding.
// Each point scanned by 8 threads (chunks of 256 candidates).
__global__ __launch_bounds__(256) void knn_kernel(const float* feat, int* g_idx){
    __shared__ float sx[2048], sy[2048], sz[2048];     // 24 KB
    __shared__ float sval[256][20];                    // 20 KB
    __shared__ int   sidx[256][20];                    // 20 KB
    int tid = threadIdx.x;
    int p0 = blockIdx.x * 32;
    int b = p0 >> 11;
    const float* fb = feat + b*3*2048;
    for (int i = tid; i < 2048; i += 256){ sx[i]=fb[i]; sy[i]=fb[2048+i]; sz[i]=fb[4096+i]; }
    __syncthreads();
    int pl = tid & 31, chunk = tid >> 5;
    int n = (p0 + pl) & 2047;
    double xi = sx[n], yi = sy[n], zi = sz[n];
    float val[20]; int idx[20];
#pragma unroll
    for (int k=0;k<20;k++){ val[k] = -3e38f; idx[k] = 0x7fffffff; }
    for (int j = chunk*256; j < chunk*256 + 256; j++){
        double dx = (double)sx[j]-xi, dy = (double)sy[j]-yi, dz = (double)sz[j]-zi;
        double d2 = dx*dx + dy*dy + dz*dz;
        float vf = (float)(-d2);
        bool tie = false;
#pragma unroll
        for (int s=0;s<20;s++) tie |= (vf == val[s]);
        if (!tie){
            bool bs = vf > val[19];
#pragma unroll
            for (int s=19; s>=1; s--){
                bool bm = vf > val[s-1];
                float nv = bm ? val[s-1] : vf;
                int   ni = bm ? idx[s-1] : j;
                val[s] = bs ? nv : val[s];
                idx[s] = bs ? ni : idx[s];
                bs = bm;
            }
            val[0] = bs ? vf : val[0];
            idx[0] = bs ? j  : idx[0];
        } else {
            bool bs = knn_better(vf, j, val[19], idx[19], n, sx, sy, sz);
#pragma unroll
            for (int s=19; s>=1; s--){
                bool bm = knn_better(vf, j, val[s-1], idx[s-1], n, sx, sy, sz);
                float nv = bm ? val[s-1] : vf;
                int   ni = bm ? idx[s-1] : j;
                val[s] = bs ? nv : val[s];
                idx[s] = bs ? ni : idx[s];
                bs = bm;
            }
            val[0] = bs ? vf : val[0];
            idx[0] = bs ? j  : idx[0];
        }
    }
#pragma unroll
    for (int k=0;k<20;k++){ sval[tid][k] = val[k]; sidx[tid][k] = idx[k]; }
    __syncthreads();
    if (tid < 32){
        int nn = (p0 + tid) & 2047;
        int ptr[8] = {0,0,0,0,0,0,0,0};
        for (int kk=0; kk<20; kk++){
            float bv = 0.f; int bi = 0x7fffffff; int bc = -1;
#pragma unroll
            for (int c=0;c<8;c++){
                if (ptr[c] < 20){
                    int row = c*32 + tid;
                    float v = sval[row][ptr[c]]; int ix = sidx[row][ptr[c]];
                    if (bc < 0 || knn_better(v, ix, bv, bi, nn, sx, sy, sz)){ bv=v; bi=ix; bc=c; }
                }
            }
            ptr[bc]++;
            g_idx[(p0+tid)*20 + kk] = bi;
        }
    }
}

// ---------------- x1 = xt @ fc1.T + b ----------------
__global__ void x1_kernel(const float* feat, const float* w, const float* bias, float* x1){
    int gid = blockIdx.x*256 + threadIdx.x;
    int p = gid >> 7, c = gid & 127;
    int b = p >> 11, n = p & 2047;
    const float* fb = feat + b*6144 + n;
    float v = bias[c];
    v += w[c*3+0]*fb[0];
    v += w[c*3+1]*fb[2048];
    v += w[c*3+2]*fb[4096];
    x1[gid] = v;
}

// ---------------- q/k/v ----------------
__global__ __launch_bounds__(256) void qkv_kernel(const float* x1, const float* wqT, const float* wkT,
                                                  const float* wvT, float* q, float* k1, float* v1){
    __shared__ float sx[16][128];
    int tid = threadIdx.x;
    int p0 = blockIdx.x * 16;
    for (int t = tid; t < 2048; t += 256) sx[t>>7][t&127] = x1[p0*128 + t];
    __syncthreads();
    int cg = tid & 31, pg = tid >> 5, c0 = cg*4;
    float aq[2][4] = {{0,0,0,0},{0,0,0,0}};
    float ak[2][4] = {{0,0,0,0},{0,0,0,0}};
    float av[2][4] = {{0,0,0,0},{0,0,0,0}};
    for (int j=0;j<128;j++){
        float xa = sx[pg][j], xb = sx[pg+8][j];
        float4 wq4 = *(const float4*)&wqT[j*128 + c0];
        float4 wk4 = *(const float4*)&wkT[j*128 + c0];
        float4 wv4 = *(const float4*)&wvT[j*128 + c0];
        const float* wqp = &wq4.x; const float* wkp = &wk4.x; const float* wvp = &wv4.x;
#pragma unroll
        for (int ci=0; ci<4; ci++){
            aq[0][ci] += wqp[ci]*xa; aq[1][ci] += wqp[ci]*xb;
            ak[0][ci] += wkp[ci]*xa; ak[1][ci] += wkp[ci]*xb;
            av[0][ci] += wvp[ci]*xa; av[1][ci] += wvp[ci]*xb;
        }
    }
#pragma unroll
    for (int pp=0; pp<2; pp++){
        int p = p0 + pg + pp*8;
        *(float4*)&q [p*128 + c0] = make_float4(aq[pp][0],aq[pp][1],aq[pp][2],aq[pp][3]);
        *(float4*)&k1[p*128 + c0] = make_float4(ak[pp][0],ak[pp][1],ak[pp][2],ak[pp][3]);
        *(float4*)&v1[p*128 + c0] = make_float4(av[pp][0],av[pp][1],av[pp][2],av[pp][3]);
    }
}

// ---------------- fused MFMA edge/attention kernel ----------------
__device__ __forceinline__ void stage_gemm(const unsigned* buf, const unsigned short* wb,
                                           int lane, int ct0, f32x4 acc[5][2]){
    short8 bf[2][4];
#pragma unroll
    for (int ci=0; ci<2; ci++)
#pragma unroll
    for (int ks=0; ks<4; ks++){
        U4S8 u; u.q = *(const uint4*)(wb + ((ct0+ci)*4 + ks)*512 + lane*8);
        bf[ci][ks] = u.s;
    }
#pragma unroll
    for (int rt=0; rt<5; rt++)
#pragma unroll
    for (int ci=0; ci<2; ci++)
        acc[rt][ci] = (f32x4){0.f,0.f,0.f,0.f};
    int abase = (lane&15)*132 + (lane>>4)*8;
#pragma unroll
    for (int rt=0; rt<5; rt++){
#pragma unroll
        for (int ks=0; ks<4; ks++){
            const unsigned* ap = buf + rt*16*132 + ks*32 + abase;
            uint4 w0 = *(const uint4*)ap;
            uint4 w1 = *(const uint4*)(ap+4);
            W4 hi, lo;
            hi.u[0] = __builtin_amdgcn_perm(w0.y, w0.x, 0x05040100u);
            lo.u[0] = __builtin_amdgcn_perm(w0.y, w0.x, 0x07060302u);
            hi.u[1] = __builtin_amdgcn_perm(w0.w, w0.z, 0x05040100u);
            lo.u[1] = __builtin_amdgcn_perm(w0.w, w0.z, 0x07060302u);
            hi.u[2] = __builtin_amdgcn_perm(w1.y, w1.x, 0x05040100u);
            lo.u[2] = __builtin_amdgcn_perm(w1.y, w1.x, 0x07060302u);
            hi.u[3] = __builtin_amdgcn_perm(w1.w, w1.z, 0x05040100u);
            lo.u[3] = __builtin_amdgcn_perm(w1.w, w1.z, 0x07060302u);
#pragma unroll
            for (int ci=0; ci<2; ci++){
                acc[rt][ci] = __builtin_amdgcn_mfma_f32_16x16x32_bf16(hi.s, bf[ci][ks], acc[rt][ci], 0,0,0);
                acc[rt][ci] = __builtin_amdgcn_mfma_f32_16x16x32_bf16(lo.s, bf[ci][ks], acc[rt][ci], 0,0,0);
            }
        }
    }
}

__global__ __launch_bounds__(256, 3) void attn_kernel(
        const float* feat, const int* g_idx, const float* g_q, const float* g_k1, const float* g_v1,
        const unsigned short* wpk,     // fb2(0), fg1(+16384), fg2(+32768) B-frag packed
        const float* fb1w, const float* fb1b, const float* fb2b, const float* fg1b, const float* fg2b,
        float* g_attn, float* g_res){
    __shared__ __align__(16) unsigned buf[80*132];   // 42240 B
    __shared__ float sh_q[512];
    __shared__ float sh_e[80*6];
    __shared__ int   sh_ix[80];
    int tid = threadIdx.x;
    int lane = tid & 63, wave = tid >> 6;
    int gp0 = blockIdx.x * 4;
    int b = gp0 >> 11;
    size_t kvbase = (size_t)b*2048*128;

    sh_q[tid]     = g_q[gp0*128 + tid];
    sh_q[tid+256] = g_q[gp0*128 + tid + 256];
    if (tid < 80){
        int r = tid;
        int nb = g_idx[gp0*20 + r];
        sh_ix[r] = nb;
        int p = (r*205) >> 12;           // r/20 for r<80
        int n = (gp0 & 2047) + p;
        const float* fbp = feat + b*6144;
        float cx = fbp[n], cy = fbp[2048+n], cz = fbp[4096+n];
        float nx = fbp[nb], ny = fbp[2048+nb], nz = fbp[4096+nb];
        sh_e[r*6+0] = nx-cx; sh_e[r*6+1] = ny-cy; sh_e[r*6+2] = nz-cz;
        sh_e[r*6+3] = cx;    sh_e[r*6+4] = cy;    sh_e[r*6+5] = cz;
    }
    __syncthreads();

    // P1: h = relu(fb1 . e + b1)  -> buf (packed)
    {
        int c = tid & 127, rh = tid >> 7;
        float w0=fb1w[c*6+0], w1=fb1w[c*6+1], w2=fb1w[c*6+2], w3=fb1w[c*6+3], w4=fb1w[c*6+4], w5=fb1w[c*6+5];
        float bb = fb1b[c];
#pragma unroll
        for (int rr=0; rr<40; rr++){
            int r = rr*2 + rh;
            const float* e = &sh_e[r*6];
            float v = bb + w0*e[0]+w1*e[1]+w2*e[2]+w3*e[3]+w4*e[4]+w5*e[5];
            buf[r*132 + c] = pack_hl(fmaxf(v, 0.f));
        }
    }
    __syncthreads();

    int ct0 = wave*2;
    int colA = ct0*16 + (lane&15);
    int colB = colA + 16;
    int quad = lane >> 4;
    f32x4 acc[5][2];

    // ---- P2: kf = fb2.h + b2 ; a_in = q - kg + kf ----
    stage_gemm(buf, wpk, lane, ct0, acc);
    {
        float bA = fb2b[colA], bB = fb2b[colB];
#pragma unroll
        for (int rt=0; rt<5; rt++)
#pragma unroll
        for (int ci=0; ci<2; ci++){
            int col = ci ? colB : colA;
            float bias = ci ? bB : bA;
#pragma unroll
            for (int reg=0; reg<4; reg++){
                int row = rt*16 + quad*4 + reg;
                float kf = acc[rt][ci][reg] + bias;
                g_attn[(size_t)(gp0*20 + row)*128 + col] = kf;   // kf scratch in out1
                int p = (row*205)>>12;
                int nb = sh_ix[row];
                float kg = g_k1[kvbase + (size_t)nb*128 + col];
                float ain = sh_q[p*128 + col] - kg + kf;
                acc[rt][ci][reg] = __uint_as_float(pack_hl(ain));
            }
        }
    }
    __syncthreads();
#pragma unroll
    for (int rt=0; rt<5; rt++)
#pragma unroll
    for (int ci=0; ci<2; ci++)
#pragma unroll
    for (int reg=0; reg<4; reg++){
        int row = rt*16 + quad*4 + reg;
        int col = ci ? colB : colA;
        buf[row*132 + col] = __float_as_uint(acc[rt][ci][reg]);
    }
    __syncthreads();

    // ---- P3: t = relu(fg1 . a_in + b) ----
    stage_gemm(buf, wpk + 16384, lane, ct0, acc);
    {
        float bA = fg1b[colA], bB = fg1b[colB];
#pragma unroll
        for (int rt=0; rt<5; rt++)
#pragma unroll
        for (int ci=0; ci<2; ci++){
            float bias = ci ? bB : bA;
#pragma unroll
            for (int reg=0; reg<4; reg++)
                acc[rt][ci][reg] = __uint_as_float(pack_hl(fmaxf(acc[rt][ci][reg] + bias, 0.f)));
        }
    }
    __syncthreads();
#pragma unroll
    for (int rt=0; rt<5; rt++)
#pragma unroll
    for (int ci=0; ci<2; ci++)
#pragma unroll
    for (int reg=0; reg<4; reg++){
        int row = rt*16 + quad*4 + reg;
        int col = ci ? colB : colA;
        buf[row*132 + col] = __float_as_uint(acc[rt][ci][reg]);
    }
    __syncthreads();

    // ---- P4: a2 = fg2 . t + b  (stored fp32 in buf) ----
    stage_gemm(buf, wpk + 32768, lane, ct0, acc);
    {
        float bA = fg2b[colA], bB = fg2b[colB];
#pragma unroll
        for (int rt=0; rt<5; rt++)
#pragma unroll
        for (int ci=0; ci<2; ci++){
            float bias = ci ? bB : bA;
#pragma unroll
            for (int reg=0; reg<4; reg++)
                acc[rt][ci][reg] += bias;
        }
    }
    __syncthreads();
#pragma unroll
    for (int rt=0; rt<5; rt++)
#pragma unroll
    for (int ci=0; ci<2; ci++)
#pragma unroll
    for (int reg=0; reg<4; reg++){
        int row = rt*16 + quad*4 + reg;
        int col = ci ? colB : colA;
        buf[row*132 + col] = __float_as_uint(acc[rt][ci][reg]);
    }
    __syncthreads();

    // ---- P5: log_softmax over K + attn write + res ----
#pragma unroll
    for (int w=0; w<2; w++){
        int wk = tid + 256*w;          // 0..511
        int p = wk >> 7, c = wk & 127;
        float s[20];
        float m = -3e38f;
#pragma unroll
        for (int k=0;k<20;k++){
            s[k] = __uint_as_float(buf[(p*20+k)*132 + c]) * 0.08838834764831845f;
            m = fmaxf(m, s[k]);
        }
        float sum = 0.f;
#pragma unroll
        for (int k=0;k<20;k++) sum += expf(s[k] - m);
        float L = m + logf(sum);
        float* op = g_attn + (size_t)(gp0+p)*20*128 + c;
        float res = 0.f;
#pragma unroll
        for (int k=0;k<20;k++){
            float at = s[k] - L;
            float kf = op[k*128];                 // read kf scratch first
            int nb = sh_ix[p*20+k];
            float vv = g_v1[kvbase + (size_t)nb*128 + c];
            res += at * (vv + kf);
            op[k*128] = at;                       // then overwrite with attn
        }
        g_res[(gp0+p)*128 + c] = res;
    }
}

// ---------------- generic per-point linear (128->128) ----------------
__global__ __launch_bounds__(256) void lin_kernel(const float* X, const float* WT, const float* bias, float* Y){
    __shared__ float sx[16][128];
    int tid = threadIdx.x;
    int p0 = blockIdx.x * 16;
    for (int t = tid; t < 2048; t += 256) sx[t>>7][t&127] = X[p0*128 + t];
    __syncthreads();
    int cg = tid & 31, pg = tid >> 5, c0 = cg*4;
    float a[2][4] = {{0,0,0,0},{0,0,0,0}};
    for (int j=0;j<128;j++){
        float xa = sx[pg][j], xb = sx[pg+8][j];
        float4 w4 = *(const float4*)&WT[j*128 + c0];
        const float* wp = &w4.x;
#pragma unroll
        for (int ci=0;ci<4;ci++){ a[0][ci] += wp[ci]*xa; a[1][ci] += wp[ci]*xb; }
    }
    float4 bv = *(const float4*)&bias[c0];
    const float* bp = &bv.x;
#pragma unroll
    for (int pp=0;pp<2;pp++){
        int p = p0 + pg + pp*8;
        *(float4*)&Y[p*128+c0] = make_float4(a[pp][0]+bp[0], a[pp][1]+bp[1], a[pp][2]+bp[2], a[pp][3]+bp[3]);
    }
}

__global__ __launch_bounds__(256) void l6_kernel(const float* Xa, const float* Xb, const float* WT,
                                                 const float* bias, float* Y){
    __shared__ float sx[16][128];
    int tid = threadIdx.x;
    int p0 = blockIdx.x * 16;
    for (int t = tid; t < 2048; t += 256) sx[t>>7][t&127] = Xa[p0*128 + t] - Xb[p0*128 + t];
    __syncthreads();
    int cg = tid & 31, pg = tid >> 5, c0 = cg*4;
    float a[2][4] = {{0,0,0,0},{0,0,0,0}};
    for (int j=0;j<128;j++){
        float xa = sx[pg][j], xb = sx[pg+8][j];
        float4 w4 = *(const float4*)&WT[j*128 + c0];
        const float* wp = &w4.x;
#pragma unroll
        for (int ci=0;ci<4;ci++){ a[0][ci] += wp[ci]*xa; a[1][ci] += wp[ci]*xb; }
    }
    float4 bv = *(const float4*)&bias[c0];
    const float* bp = &bv.x;
#pragma unroll
    for (int pp=0;pp<2;pp++){
        int p = p0 + pg + pp*8;
        *(float4*)&Y[p*128+c0] = make_float4(a[pp][0]+bp[0], a[pp][1]+bp[1], a[pp][2]+bp[2], a[pp][3]+bp[3]);
    }
}

__global__ __launch_bounds__(256) void l5_kernel(const float* X, const float* WvT, const float* vb,
                                                 const float* WqkT, float* Yv, float* Yqk){
    __shared__ float sx[16][128];
    int tid = threadIdx.x;
    int p0 = blockIdx.x * 16;
    for (int t = tid; t < 2048; t += 256) sx[t>>7][t&127] = X[p0*128 + t];
    __syncthreads();
    int cg = tid & 31, pg = tid >> 5, c0 = cg*4;
    {
        float a[2][4] = {{0,0,0,0},{0,0,0,0}};
        for (int j=0;j<128;j++){
            float xa = sx[pg][j], xb = sx[pg+8][j];
            float4 w4 = *(const float4*)&WvT[j*128 + c0];
            const float* wp = &w4.x;
#pragma unroll
            for (int ci=0;ci<4;ci++){ a[0][ci] += wp[ci]*xa; a[1][ci] += wp[ci]*xb; }
        }
        float4 bv = *(const float4*)&vb[c0];
        const float* bp = &bv.x;
#pragma unroll
        for (int pp=0;pp<2;pp++){
            int p = p0 + pg + pp*8;
            *(float4*)&Yv[p*128+c0] = make_float4(a[pp][0]+bp[0], a[pp][1]+bp[1], a[pp][2]+bp[2], a[pp][3]+bp[3]);
        }
    }
    if (cg < 8){
        int cq = cg*4;
        float a[2][4] = {{0,0,0,0},{0,0,0,0}};
        for (int j=0;j<128;j++){
            float xa = sx[pg][j], xb = sx[pg+8][j];
            float4 w4 = *(const float4*)&WqkT[j*32 + cq];
            const float* wp = &w4.x;
#pragma unroll
            for (int ci=0;ci<4;ci++){ a[0][ci] += wp[ci]*xa; a[1][ci] += wp[ci]*xb; }
        }
#pragma unroll
        for (int pp=0;pp<2;pp++){
            int p = p0 + pg + pp*8;
            *(float4*)&Yqk[p*32+cq] = make_float4(a[pp][0], a[pp][1], a[pp][2], a[pp][3]);
        }
    }
}

// ---------------- batchnorm ----------------
__global__ void bn_stats_kernel(const float* X, float* sums){
    int tid = threadIdx.x;
    int c = tid & 127, half = tid >> 7;
    int r0 = blockIdx.x*128 + half*64;
    float s = 0.f, sq = 0.f;
    for (int r = r0; r < r0+64; r++){
        float v = X[r*128 + c];
        s += v; sq += v*v;
    }
    atomicAdd(&sums[c], s);
    atomicAdd(&sums[128+c], sq);
}

__global__ void bn1_apply_kernel(const float* res2, const float* x1, const float* sums,
                                 const float* g, const float* beta, float* sres){
    int gid = blockIdx.x*256 + threadIdx.x;
    int c = gid & 127;
    float mu = sums[c] * (1.0f/16384.f);
    float var = sums[128+c] * (1.0f/16384.f) - mu*mu;
    float inv = 1.0f / sqrtf(var + 1e-5f);
    float y = g[c]*(res2[gid]-mu)*inv + beta[c];
    sres[gid] = fmaxf(y, 0.f) + x1[gid];
}

__global__ void final_kernel(const float* sres, const float* xr2, const float* sums,
                             const float* g, const float* beta, float* out0){
    int gid = blockIdx.x*256 + threadIdx.x;
    int c = gid & 127;
    float mu = sums[c] * (1.0f/16384.f);
    float var = sums[128+c] * (1.0f/16384.f) - mu*mu;
    float inv = 1.0f / sqrtf(var + 1e-5f);
    float y = g[c]*(xr2[gid]-mu)*inv + beta[c];
    out0[gid] = sres[gid] + fmaxf(y, 0.f);
}

// ---------------- SA softmax row stats (2-pass recompute) ----------------
__global__ __launch_bounds__(256) void rowstats_kernel(const float* xqk, float* rm, float* rs){
    __shared__ float sxj[256][33];
    int tid = threadIdx.x;
    int b = blockIdx.x >> 8;
    int i0 = (blockIdx.x & 255) * 8;
    int ip = tid >> 6, l = tid & 63;
    const float* base = xqk + b*2048*32;
    float xi0[32], xi1[32];
#pragma unroll
    for (int c=0;c<32;c++){ xi0[c] = base[(i0+2*ip)*32+c]; xi1[c] = base[(i0+2*ip+1)*32+c]; }
    float m0 = -3e38f, m1 = -3e38f;
    for (int jc=0;jc<8;jc++){
        __syncthreads();
        for (int t=tid;t<8192;t+=256) sxj[t>>5][t&31] = base[jc*8192 + t];
        __syncthreads();
        for (int s=0;s<4;s++){
            int j = l + s*64;
            float d0=0.f, d1=0.f;
#pragma unroll
            for (int c=0;c<32;c++){ float xv = sxj[j][c]; d0 += xi0[c]*xv; d1 += xi1[c]*xv; }
            m0 = fmaxf(m0, d0); m1 = fmaxf(m1, d1);
        }
    }
#pragma unroll
    for (int mk=32; mk>=1; mk>>=1){ m0 = fmaxf(m0, __shfl_xor(m0,mk)); m1 = fmaxf(m1, __shfl_xor(m1,mk)); }
    float s0 = 0.f, s1 = 0.f;
    for (int jc=0;jc<8;jc++){
        __syncthreads();
        for (int t=tid;t<8192;t+=256) sxj[t>>5][t&31] = base[jc*8192 + t];
        __syncthreads();
        for (int s=0;s<4;s++){
            int j = l + s*64;
            float d0=0.f, d1=0.f;
#pragma unroll
            for (int c=0;c<32;c++){ float xv = sxj[j][c]; d0 += xi0[c]*xv; d1 += xi1[c]*xv; }
            s0 += expf(d0 - m0); s1 += expf(d1 - m1);
        }
    }
#pragma unroll
    for (int mk=32; mk>=1; mk>>=1){ s0 += __shfl_xor(s0,mk); s1 += __shfl_xor(s1,mk); }
    if (l == 0){
        rm[b*2048+i0+2*ip]   = m0; rs[b*2048+i0+2*ip]   = s0;
        rm[b*2048+i0+2*ip+1] = m1; rs[b*2048+i0+2*ip+1] = s1;
    }
}

__global__ __launch_bounds__(256) void colsum_kernel(const float* xqk, const float* rm, const float* rs, float* cs){
    __shared__ float sxi[256][33];
    __shared__ float srm[256], sirs[256];
    int tid = threadIdx.x;
    int blk = blockIdx.x;
    int b = blk >> 6, jt = (blk>>3)&7, ic = blk&7;
    const float* base = xqk + b*2048*32;
    int j = jt*256 + tid;
    float xj[32];
#pragma unroll
    for (int c=0;c<32;c++) xj[c] = base[j*32+c];
    int i0 = ic*256;
    for (int t=tid;t<8192;t+=256) sxi[t>>5][t&31] = base[i0*32 + t];
    srm[tid] = rm[b*2048 + i0 + tid];
    sirs[tid] = 1.0f / rs[b*2048 + i0 + tid];
    __syncthreads();
    float acc = 0.f;
    for (int i=0;i<256;i++){
        float d = 0.f;
#pragma unroll
        for (int c=0;c<32;c++) d += sxi[i][c]*xj[c];
        acc += expf(d - srm[i]) * sirs[i];
    }
    atomicAdd(&cs[b*2048 + j], acc);
}

__global__ __launch_bounds__(256) void xr_kernel(const float* xqk, const float* xv, const float* rm,
                                                 const float* rs, const float* cs, float* xr){
    __shared__ float sqm[32][33];
    __shared__ float sqn[64][33];
    __shared__ float sxv[64][128];
    __shared__ float satt[64][32];
    __shared__ float srm[64], sirs[64], sics[32];
    int tid = threadIdx.x;
    int b = blockIdx.x >> 6, mt = blockIdx.x & 63;
    const float* qb = xqk + b*2048*32;
    for (int t=tid; t<1024; t+=256) sqm[t>>5][t&31] = qb[(mt*32)*32 + t];
    if (tid < 32) sics[tid] = 1.0f / (1e-9f + cs[b*2048 + mt*32 + tid]);
    float acc[4][4];
#pragma unroll
    for (int i=0;i<4;i++)
#pragma unroll
        for (int jj=0;jj<4;jj++) acc[i][jj] = 0.f;
    int mg = tid >> 5, cgx = tid & 31, m0 = mg*4, c0 = cgx*4;
    int nq = tid >> 2, mq = tid & 3;
    for (int nc=0; nc<32; nc++){
        int n0 = nc*64;
        __syncthreads();
        for (int t=tid; t<2048; t+=256) sqn[t>>5][t&31] = qb[n0*32 + t];
        for (int t=tid; t<2048; t+=256){
            int r = t>>5, cq = (t&31)*4;
            *(float4*)&sxv[r][cq] = *(const float4*)&xv[(size_t)(b*2048+n0+r)*128 + cq];
        }
        if (tid < 64){ srm[tid] = rm[b*2048+n0+tid]; sirs[tid] = 1.0f/rs[b*2048+n0+tid]; }
        __syncthreads();
        {
            float qn[32];
#pragma unroll
            for (int c=0;c<32;c++) qn[c] = sqn[nq][c];
            float rmv = srm[nq], irsv = sirs[nq];
            float av[8];
#pragma unroll
            for (int mi=0;mi<8;mi++){
                int m = mq*8+mi;
                float d = 0.f;
#pragma unroll
                for (int c=0;c<32;c++) d += qn[c]*sqm[m][c];
                av[mi] = expf(d - rmv) * irsv;
            }
            *(float4*)&satt[nq][mq*8]   = make_float4(av[0],av[1],av[2],av[3]);
            *(float4*)&satt[nq][mq*8+4] = make_float4(av[4],av[5],av[6],av[7]);
        }
        __syncthreads();
        for (int nn=0; nn<64; nn++){
            float4 a4 = *(const float4*)&satt[nn][m0];
            float4 x4 = *(const float4*)&sxv[nn][c0];
            const float* ap = &a4.x; const float* xp = &x4.x;
#pragma unroll
            for (int mi=0;mi<4;mi++)
#pragma unroll
                for (int ci=0;ci<4;ci++) acc[mi][ci] += ap[mi]*xp[ci];
        }
    }
#pragma unroll
    for (int mi=0;mi<4;mi++){
        float sc = sics[m0+mi];
        *(float4*)&xr[(size_t)(b*2048 + mt*32 + m0+mi)*128 + c0] =
            make_float4(acc[mi][0]*sc, acc[mi][1]*sc, acc[mi][2]*sc, acc[mi][3]*sc);
    }
}

// ---------------- launch ----------------
extern "C" void kernel_launch(void* const* d_in, const int* in_sizes, int n_in,
                              void* d_out, int out_size, void* d_ws, size_t ws_size,
                              hipStream_t stream){
    (void)in_sizes; (void)n_in; (void)out_size; (void)ws_size;
    const float* feat = (const float*)d_in[0];
    const float* fc1w = (const float*)d_in[1];  const float* fc1b = (const float*)d_in[2];
    const float* fc2w = (const float*)d_in[3];  const float* fc2b = (const float*)d_in[4];
    const float* bng  = (const float*)d_in[5];  const float* bnb  = (const float*)d_in[6];
    const float* fb1w = (const float*)d_in[7];  const float* fb1b = (const float*)d_in[8];
    const float* fb2w = (const float*)d_in[9];  const float* fb2b = (const float*)d_in[10];
    const float* fg1w = (const float*)d_in[11]; const float* fg1b = (const float*)d_in[12];
    const float* fg2w = (const float*)d_in[13]; const float* fg2b = (const float*)d_in[14];
    const float* wq   = (const float*)d_in[15]; const float* wk   = (const float*)d_in[16];
    const float* wv   = (const float*)d_in[17];
    const float* saqk = (const float*)d_in[18];
    const float* savw = (const float*)d_in[19]; const float* savb = (const float*)d_in[20];
    const float* satw = (const float*)d_in[21]; const float* satb = (const float*)d_in[22];
    const float* sabng= (const float*)d_in[23]; const float* sabnb= (const float*)d_in[24];

    float* out0 = (float*)d_out;
    float* out1 = out0 + 2097152;

    char* ws = (char*)d_ws;
    size_t off = 0;
    auto A = [&](size_t bytes)->char*{
        char* r = ws + off;
        off = (off + bytes + 255) & ~(size_t)255;
        return r;
    };
    const size_t PBUF = (size_t)NPTS*128*4;   // 8 MB
    int*      g_idx  = (int*)A((size_t)NPTS*KNN*4);
    float*    g_x1   = (float*)A(PBUF);
    float*    g_q    = (float*)A(PBUF);
    float*    g_k1   = (float*)A(PBUF);
    float*    g_v1   = (float*)A(PBUF);
    float*    g_res  = (float*)A(PBUF);
    float*    g_res2 = (float*)A(PBUF);
    float*    g_sres = (float*)A(PBUF);
    float*    g_xv   = (float*)A(PBUF);
    float*    g_xr   = (float*)A(PBUF);
    float*    g_xr2  = (float*)A(PBUF);
    float*    g_xqk  = (float*)A((size_t)NPTS*32*4);
    float*    g_rm   = (float*)A((size_t)NPTS*4);
    float*    g_rs   = (float*)A((size_t)NPTS*4);
    float*    g_stats= (float*)A((size_t)(256+256+NPTS)*4);
    unsigned short* g_wpk = (unsigned short*)A((size_t)3*16384*2);
    float*    g_wqT  = (float*)A(65536);
    float*    g_wkT  = (float*)A(65536);
    float*    g_wvT  = (float*)A(65536);
    float*    g_fc2T = (float*)A(65536);
    float*    g_savT = (float*)A(65536);
    float*    g_satT = (float*)A(65536);
    float*    g_sqkT = (float*)A(16384);

    float* bn1s = g_stats;
    float* bn2s = g_stats + 256;
    float* g_cs = g_stats + 512;

    hipMemsetAsync(g_stats, 0, (size_t)(256+256+NPTS)*4, stream);

    pack_bfrag_kernel<<<192, 256, 0, stream>>>(fb2w, fg1w, fg2w, g_wpk);
    transpose_kernel<<<64, 256, 0, stream>>>(wq,   g_wqT, 128);
    transpose_kernel<<<64, 256, 0, stream>>>(wk,   g_wkT, 128);
    transpose_kernel<<<64, 256, 0, stream>>>(wv,   g_wvT, 128);
    transpose_kernel<<<64, 256, 0, stream>>>(fc2w, g_fc2T, 128);
    transpose_kernel<<<64, 256, 0, stream>>>(savw, g_savT, 128);
    transpose_kernel<<<64, 256, 0, stream>>>(satw, g_satT, 128);
    transpose_kernel<<<16, 256, 0, stream>>>(saqk, g_sqkT, 32);

    knn_kernel<<<512, 256, 0, stream>>>(feat, g_idx);
    x1_kernel<<<8192, 256, 0, stream>>>(feat, fc1w, fc1b, g_x1);
    qkv_kernel<<<1024, 256, 0, stream>>>(g_x1, g_wqT, g_wkT, g_wvT, g_q, g_k1, g_v1);
    attn_kernel<<<4096, 256, 0, stream>>>(feat, g_idx, g_q, g_k1, g_v1, g_wpk,
                                          fb1w, fb1b, fb2b, fg1b, fg2b, out1, g_res);
    lin_kernel<<<1024, 256, 0, stream>>>(g_res, g_fc2T, fc2b, g_res2);
    bn_stats_kernel<<<128, 256, 0, stream>>>(g_res2, bn1s);
    bn1_apply_kernel<<<8192, 256, 0, stream>>>(g_res2, g_x1, bn1s, bng, bnb, g_sres);
    l5_kernel<<<1024, 256, 0, stream>>>(g_sres, g_savT, savb, g_sqkT, g_xv, g_xqk);
    rowstats_kernel<<<2048, 256, 0, stream>>>(g_xqk, g_rm, g_rs);
    colsum_kernel<<<512, 256, 0, stream>>>(g_xqk, g_rm, g_rs, g_cs);
    xr_kernel<<<512, 256, 0, stream>>>(g_xqk, g_xv, g_rm, g_rs, g_cs, g_xr);
    l6_kernel<<<1024, 256, 0, stream>>>(g_sres, g_xr, g_satT, satb, g_xr2);
    bn_stats_kernel<<<128, 256, 0, stream>>>(g_xr2, bn2s);
    final_kernel<<<8192, 256, 0, stream>>>(g_sres, g_xr2, bn2s, sabng, sabnb, out0);
}

// Round 5
// 982.044 us; speedup vs baseline: 3.1657x; 1.2208x over previous
//
#include <hip/hip_runtime.h>

#define NPTS 16384   // B*N = 8*2048
#define NB 2048
#define KNN 20

typedef __attribute__((ext_vector_type(4))) float f32x4;
typedef __attribute__((ext_vector_type(8))) short short8;

union U4S8 { uint4 q; short8 s; };
union W4   { unsigned u[4]; short8 s; };

__device__ __forceinline__ unsigned bf16_rne(float v){
    unsigned u = __float_as_uint(v);
    return (u + 0x7fffu + ((u>>16)&1u)) >> 16;
}
// pack fp32 -> (hi bf16) | (lo bf16 << 16), hi+lo ~= v to ~2^-17 rel
__device__ __forceinline__ unsigned pack_hl(float v){
    unsigned hi = bf16_rne(v);
    float r = v - __uint_as_float(hi<<16);
    unsigned lo = bf16_rne(r);
    return hi | (lo<<16);
}
// split 8 packed (hi|lo<<16) words into hi/lo bf16x8 fragments
__device__ __forceinline__ void split_hl(uint4 w0, uint4 w1, short8& hi, short8& lo){
    W4 h, l;
    h.u[0] = __builtin_amdgcn_perm(w0.y, w0.x, 0x05040100u);
    l.u[0] = __builtin_amdgcn_perm(w0.y, w0.x, 0x07060302u);
    h.u[1] = __builtin_amdgcn_perm(w0.w, w0.z, 0x05040100u);
    l.u[1] = __builtin_amdgcn_perm(w0.w, w0.z, 0x07060302u);
    h.u[2] = __builtin_amdgcn_perm(w1.y, w1.x, 0x05040100u);
    l.u[2] = __builtin_amdgcn_perm(w1.y, w1.x, 0x07060302u);
    h.u[3] = __builtin_amdgcn_perm(w1.w, w1.z, 0x05040100u);
    l.u[3] = __builtin_amdgcn_perm(w1.w, w1.z, 0x07060302u);
    hi = h.s; lo = l.s;
}
// fp32-like product via 3 bf16 MFMAs (fixed order -> deterministic across kernels)
__device__ __forceinline__ f32x4 e3_mfma(short8 Ah, short8 Al, short8 Bh, short8 Bl){
    f32x4 acc = (f32x4){0.f,0.f,0.f,0.f};
    acc = __builtin_amdgcn_mfma_f32_16x16x32_bf16(Al, Bh, acc, 0,0,0);
    acc = __builtin_amdgcn_mfma_f32_16x16x32_bf16(Ah, Bl, acc, 0,0,0);
    acc = __builtin_amdgcn_mfma_f32_16x16x32_bf16(Ah, Bh, acc, 0,0,0);
    return acc;
}

// transpose [C][128] -> [j][C]  (fp32), C = 128 or 32
__global__ void transpose_kernel(const float* in, float* out, int C){
    int gid = blockIdx.x*256 + threadIdx.x;
    if (gid >= 128*C) return;
    int j = gid / C, c = gid - j*C;
    out[gid] = in[c*128 + j];
}

// pack fb2/fg1/fg2 into MFMA B-fragment layout (bf16)
__global__ void pack_bfrag_kernel(const float* w0, const float* w1, const float* w2, unsigned short* out){
    int gid = blockIdx.x*256 + threadIdx.x;
    if (gid >= 3*16384) return;
    int m = gid >> 14, r = gid & 16383;
    const float* W = (m==0)?w0:(m==1)?w1:w2;
    int e = r & 7, lane = (r>>3) & 63, ks = (r>>9)&3, ct = r>>11;
    int c = ct*16 + (lane&15), j = ks*32 + (lane>>4)*8 + e;
    out[gid] = (unsigned short)bf16_rne(W[c*128 + j]);
}

// ---------------- kNN ----------------
__device__ __forceinline__ double dist2_of(int n, int j, const float* sx, const float* sy, const float* sz){
    j &= 2047;
    double dx = (double)sx[j] - (double)sx[n];
    double dy = (double)sy[j] - (double)sy[n];
    double dz = (double)sz[j] - (double)sz[n];
    return dx*dx + dy*dy + dz*dz;
}
__device__ __forceinline__ bool knn_better(float va, int ja, float vb, int jb, int n,
                                           const float* sx, const float* sy, const float* sz){
    if (va != vb) return va > vb;
    if (ja == jb) return false;
    double da = dist2_of(n, ja, sx, sy, sz);
    double db = dist2_of(n, jb, sx, sy, sz);
    if (da != db) return da < db;
    return ja < jb;
}

__global__ __launch_bounds__(256) void knn_kernel(const float* feat, int* g_idx){
    __shared__ float sx[2048], sy[2048], sz[2048];
    __shared__ float sval[256][20];
    __shared__ int   sidx[256][20];
    int tid = threadIdx.x;
    int p0 = blockIdx.x * 32;
    int b = p0 >> 11;
    const float* fb = feat + b*3*2048;
    for (int i = tid; i < 2048; i += 256){ sx[i]=fb[i]; sy[i]=fb[2048+i]; sz[i]=fb[4096+i]; }
    __syncthreads();
    int pl = tid & 31, chunk = tid >> 5;
    int n = (p0 + pl) & 2047;
    double xi = sx[n], yi = sy[n], zi = sz[n];
    float val[20]; int idx[20];
#pragma unroll
    for (int k=0;k<20;k++){ val[k] = -3e38f; idx[k] = 0x7fffffff; }
    for (int j = chunk*256; j < chunk*256 + 256; j++){
        double dx = (double)sx[j]-xi, dy = (double)sy[j]-yi, dz = (double)sz[j]-zi;
        double d2 = dx*dx + dy*dy + dz*dz;
        float vf = (float)(-d2);
        bool tie = false;
#pragma unroll
        for (int s=0;s<20;s++) tie |= (vf == val[s]);
        if (!tie){
            bool bs = vf > val[19];
#pragma unroll
            for (int s=19; s>=1; s--){
                bool bm = vf > val[s-1];
                float nv = bm ? val[s-1] : vf;
                int   ni = bm ? idx[s-1] : j;
                val[s] = bs ? nv : val[s];
                idx[s] = bs ? ni : idx[s];
                bs = bm;
            }
            val[0] = bs ? vf : val[0];
            idx[0] = bs ? j  : idx[0];
        } else {
            bool bs = knn_better(vf, j, val[19], idx[19], n, sx, sy, sz);
#pragma unroll
            for (int s=19; s>=1; s--){
                bool bm = knn_better(vf, j, val[s-1], idx[s-1], n, sx, sy, sz);
                float nv = bm ? val[s-1] : vf;
                int   ni = bm ? idx[s-1] : j;
                val[s] = bs ? nv : val[s];
                idx[s] = bs ? ni : idx[s];
                bs = bm;
            }
            val[0] = bs ? vf : val[0];
            idx[0] = bs ? j  : idx[0];
        }
    }
#pragma unroll
    for (int k=0;k<20;k++){ sval[tid][k] = val[k]; sidx[tid][k] = idx[k]; }
    __syncthreads();
    if (tid < 32){
        int nn = (p0 + tid) & 2047;
        int ptr[8] = {0,0,0,0,0,0,0,0};
        for (int kk=0; kk<20; kk++){
            float bv = 0.f; int bi = 0x7fffffff; int bc = -1;
#pragma unroll
            for (int c=0;c<8;c++){
                if (ptr[c] < 20){
                    int row = c*32 + tid;
                    float v = sval[row][ptr[c]]; int ix = sidx[row][ptr[c]];
                    if (bc < 0 || knn_better(v, ix, bv, bi, nn, sx, sy, sz)){ bv=v; bi=ix; bc=c; }
                }
            }
            ptr[bc]++;
            g_idx[(p0+tid)*20 + kk] = bi;
        }
    }
}

// ---------------- x1 = xt @ fc1.T + b ----------------
__global__ void x1_kernel(const float* feat, const float* w, const float* bias, float* x1){
    int gid = blockIdx.x*256 + threadIdx.x;
    int p = gid >> 7, c = gid & 127;
    int b = p >> 11, n = p & 2047;
    const float* fb = feat + b*6144 + n;
    float v = bias[c];
    v += w[c*3+0]*fb[0];
    v += w[c*3+1]*fb[2048];
    v += w[c*3+2]*fb[4096];
    x1[gid] = v;
}

// ---------------- q/k/v ----------------
__global__ __launch_bounds__(256) void qkv_kernel(const float* x1, const float* wqT, const float* wkT,
                                                  const float* wvT, float* q, float* k1, float* v1){
    __shared__ float sx[16][128];
    int tid = threadIdx.x;
    int p0 = blockIdx.x * 16;
    for (int t = tid; t < 2048; t += 256) sx[t>>7][t&127] = x1[p0*128 + t];
    __syncthreads();
    int cg = tid & 31, pg = tid >> 5, c0 = cg*4;
    float aq[2][4] = {{0,0,0,0},{0,0,0,0}};
    float ak[2][4] = {{0,0,0,0},{0,0,0,0}};
    float av[2][4] = {{0,0,0,0},{0,0,0,0}};
    for (int j=0;j<128;j++){
        float xa = sx[pg][j], xb = sx[pg+8][j];
        float4 wq4 = *(const float4*)&wqT[j*128 + c0];
        float4 wk4 = *(const float4*)&wkT[j*128 + c0];
        float4 wv4 = *(const float4*)&wvT[j*128 + c0];
        const float* wqp = &wq4.x; const float* wkp = &wk4.x; const float* wvp = &wv4.x;
#pragma unroll
        for (int ci=0; ci<4; ci++){
            aq[0][ci] += wqp[ci]*xa; aq[1][ci] += wqp[ci]*xb;
            ak[0][ci] += wkp[ci]*xa; ak[1][ci] += wkp[ci]*xb;
            av[0][ci] += wvp[ci]*xa; av[1][ci] += wvp[ci]*xb;
        }
    }
#pragma unroll
    for (int pp=0; pp<2; pp++){
        int p = p0 + pg + pp*8;
        *(float4*)&q [p*128 + c0] = make_float4(aq[pp][0],aq[pp][1],aq[pp][2],aq[pp][3]);
        *(float4*)&k1[p*128 + c0] = make_float4(ak[pp][0],ak[pp][1],ak[pp][2],ak[pp][3]);
        *(float4*)&v1[p*128 + c0] = make_float4(av[pp][0],av[pp][1],av[pp][2],av[pp][3]);
    }
}

// ---------------- fused MFMA edge/attention kernel ----------------
__device__ __forceinline__ void stage_gemm(const unsigned* buf, const unsigned short* wb,
                                           int lane, int ct0, f32x4 acc[5][2]){
    short8 bf[2][4];
#pragma unroll
    for (int ci=0; ci<2; ci++)
#pragma unroll
    for (int ks=0; ks<4; ks++){
        U4S8 u; u.q = *(const uint4*)(wb + ((ct0+ci)*4 + ks)*512 + lane*8);
        bf[ci][ks] = u.s;
    }
#pragma unroll
    for (int rt=0; rt<5; rt++)
#pragma unroll
    for (int ci=0; ci<2; ci++)
        acc[rt][ci] = (f32x4){0.f,0.f,0.f,0.f};
    int abase = (lane&15)*132 + (lane>>4)*8;
#pragma unroll
    for (int rt=0; rt<5; rt++){
#pragma unroll
        for (int ks=0; ks<4; ks++){
            const unsigned* ap = buf + rt*16*132 + ks*32 + abase;
            uint4 w0 = *(const uint4*)ap;
            uint4 w1 = *(const uint4*)(ap+4);
            short8 hi, lo;
            split_hl(w0, w1, hi, lo);
#pragma unroll
            for (int ci=0; ci<2; ci++){
                acc[rt][ci] = __builtin_amdgcn_mfma_f32_16x16x32_bf16(hi, bf[ci][ks], acc[rt][ci], 0,0,0);
                acc[rt][ci] = __builtin_amdgcn_mfma_f32_16x16x32_bf16(lo, bf[ci][ks], acc[rt][ci], 0,0,0);
            }
        }
    }
}

__global__ __launch_bounds__(256, 3) void attn_kernel(
        const float* feat, const int* g_idx, const float* g_q, const float* g_k1, const float* g_v1,
        const unsigned short* wpk,
        const float* fb1w, const float* fb1b, const float* fb2b, const float* fg1b, const float* fg2b,
        float* g_attn, float* g_res){
    __shared__ __align__(16) unsigned buf[80*132];   // 42240 B
    __shared__ float sh_q[512];
    __shared__ float sh_e[80*6];
    __shared__ int   sh_ix[80];
    int tid = threadIdx.x;
    int lane = tid & 63, wave = tid >> 6;
    int gp0 = blockIdx.x * 4;
    int b = gp0 >> 11;
    size_t kvbase = (size_t)b*2048*128;

    sh_q[tid]     = g_q[gp0*128 + tid];
    sh_q[tid+256] = g_q[gp0*128 + tid + 256];
    if (tid < 80){
        int r = tid;
        int nb = g_idx[gp0*20 + r];
        sh_ix[r] = nb;
        int p = (r*205) >> 12;
        int n = (gp0 & 2047) + p;
        const float* fbp = feat + b*6144;
        float cx = fbp[n], cy = fbp[2048+n], cz = fbp[4096+n];
        float nx = fbp[nb], ny = fbp[2048+nb], nz = fbp[4096+nb];
        sh_e[r*6+0] = nx-cx; sh_e[r*6+1] = ny-cy; sh_e[r*6+2] = nz-cz;
        sh_e[r*6+3] = cx;    sh_e[r*6+4] = cy;    sh_e[r*6+5] = cz;
    }
    __syncthreads();

    {
        int c = tid & 127, rh = tid >> 7;
        float w0=fb1w[c*6+0], w1=fb1w[c*6+1], w2=fb1w[c*6+2], w3=fb1w[c*6+3], w4=fb1w[c*6+4], w5=fb1w[c*6+5];
        float bb = fb1b[c];
#pragma unroll
        for (int rr=0; rr<40; rr++){
            int r = rr*2 + rh;
            const float* e = &sh_e[r*6];
            float v = bb + w0*e[0]+w1*e[1]+w2*e[2]+w3*e[3]+w4*e[4]+w5*e[5];
            buf[r*132 + c] = pack_hl(fmaxf(v, 0.f));
        }
    }
    __syncthreads();

    int ct0 = wave*2;
    int colA = ct0*16 + (lane&15);
    int colB = colA + 16;
    int quad = lane >> 4;
    f32x4 acc[5][2];

    stage_gemm(buf, wpk, lane, ct0, acc);
    {
        float bA = fb2b[colA], bB = fb2b[colB];
#pragma unroll
        for (int rt=0; rt<5; rt++)
#pragma unroll
        for (int ci=0; ci<2; ci++){
            int col = ci ? colB : colA;
            float bias = ci ? bB : bA;
#pragma unroll
            for (int reg=0; reg<4; reg++){
                int row = rt*16 + quad*4 + reg;
                float kf = acc[rt][ci][reg] + bias;
                g_attn[(size_t)(gp0*20 + row)*128 + col] = kf;
                int p = (row*205)>>12;
                int nb = sh_ix[row];
                float kg = g_k1[kvbase + (size_t)nb*128 + col];
                float ain = sh_q[p*128 + col] - kg + kf;
                acc[rt][ci][reg] = __uint_as_float(pack_hl(ain));
            }
        }
    }
    __syncthreads();
#pragma unroll
    for (int rt=0; rt<5; rt++)
#pragma unroll
    for (int ci=0; ci<2; ci++)
#pragma unroll
    for (int reg=0; reg<4; reg++){
        int row = rt*16 + quad*4 + reg;
        int col = ci ? colB : colA;
        buf[row*132 + col] = __float_as_uint(acc[rt][ci][reg]);
    }
    __syncthreads();

    stage_gemm(buf, wpk + 16384, lane, ct0, acc);
    {
        float bA = fg1b[colA], bB = fg1b[colB];
#pragma unroll
        for (int rt=0; rt<5; rt++)
#pragma unroll
        for (int ci=0; ci<2; ci++){
            float bias = ci ? bB : bA;
#pragma unroll
            for (int reg=0; reg<4; reg++)
                acc[rt][ci][reg] = __uint_as_float(pack_hl(fmaxf(acc[rt][ci][reg] + bias, 0.f)));
        }
    }
    __syncthreads();
#pragma unroll
    for (int rt=0; rt<5; rt++)
#pragma unroll
    for (int ci=0; ci<2; ci++)
#pragma unroll
    for (int reg=0; reg<4; reg++){
        int row = rt*16 + quad*4 + reg;
        int col = ci ? colB : colA;
        buf[row*132 + col] = __float_as_uint(acc[rt][ci][reg]);
    }
    __syncthreads();

    stage_gemm(buf, wpk + 32768, lane, ct0, acc);
    {
        float bA = fg2b[colA], bB = fg2b[colB];
#pragma unroll
        for (int rt=0; rt<5; rt++)
#pragma unroll
        for (int ci=0; ci<2; ci++){
            float bias = ci ? bB : bA;
#pragma unroll
            for (int reg=0; reg<4; reg++)
                acc[rt][ci][reg] += bias;
        }
    }
    __syncthreads();
#pragma unroll
    for (int rt=0; rt<5; rt++)
#pragma unroll
    for (int ci=0; ci<2; ci++)
#pragma unroll
    for (int reg=0; reg<4; reg++){
        int row = rt*16 + quad*4 + reg;
        int col = ci ? colB : colA;
        buf[row*132 + col] = __float_as_uint(acc[rt][ci][reg]);
    }
    __syncthreads();

#pragma unroll
    for (int w=0; w<2; w++){
        int wk = tid + 256*w;
        int p = wk >> 7, c = wk & 127;
        float s[20];
        float m = -3e38f;
#pragma unroll
        for (int k=0;k<20;k++){
            s[k] = __uint_as_float(buf[(p*20+k)*132 + c]) * 0.08838834764831845f;
            m = fmaxf(m, s[k]);
        }
        float sum = 0.f;
#pragma unroll
        for (int k=0;k<20;k++) sum += expf(s[k] - m);
        float L = m + logf(sum);
        float* op = g_attn + (size_t)(gp0+p)*20*128 + c;
        float res = 0.f;
#pragma unroll
        for (int k=0;k<20;k++){
            float at = s[k] - L;
            float kf = op[k*128];
            int nb = sh_ix[p*20+k];
            float vv = g_v1[kvbase + (size_t)nb*128 + c];
            res += at * (vv + kf);
            op[k*128] = at;
        }
        g_res[(gp0+p)*128 + c] = res;
    }
}

// ---------------- generic per-point linear (128->128) ----------------
__global__ __launch_bounds__(256) void lin_kernel(const float* X, const float* WT, const float* bias, float* Y){
    __shared__ float sx[16][128];
    int tid = threadIdx.x;
    int p0 = blockIdx.x * 16;
    for (int t = tid; t < 2048; t += 256) sx[t>>7][t&127] = X[p0*128 + t];
    __syncthreads();
    int cg = tid & 31, pg = tid >> 5, c0 = cg*4;
    float a[2][4] = {{0,0,0,0},{0,0,0,0}};
    for (int j=0;j<128;j++){
        float xa = sx[pg][j], xb = sx[pg+8][j];
        float4 w4 = *(const float4*)&WT[j*128 + c0];
        const float* wp = &w4.x;
#pragma unroll
        for (int ci=0;ci<4;ci++){ a[0][ci] += wp[ci]*xa; a[1][ci] += wp[ci]*xb; }
    }
    float4 bv = *(const float4*)&bias[c0];
    const float* bp = &bv.x;
#pragma unroll
    for (int pp=0;pp<2;pp++){
        int p = p0 + pg + pp*8;
        *(float4*)&Y[p*128+c0] = make_float4(a[pp][0]+bp[0], a[pp][1]+bp[1], a[pp][2]+bp[2], a[pp][3]+bp[3]);
    }
}

__global__ __launch_bounds__(256) void l6_kernel(const float* Xa, const float* Xb, const float* WT,
                                                 const float* bias, float* Y){
    __shared__ float sx[16][128];
    int tid = threadIdx.x;
    int p0 = blockIdx.x * 16;
    for (int t = tid; t < 2048; t += 256) sx[t>>7][t&127] = Xa[p0*128 + t] - Xb[p0*128 + t];
    __syncthreads();
    int cg = tid & 31, pg = tid >> 5, c0 = cg*4;
    float a[2][4] = {{0,0,0,0},{0,0,0,0}};
    for (int j=0;j<128;j++){
        float xa = sx[pg][j], xb = sx[pg+8][j];
        float4 w4 = *(const float4*)&WT[j*128 + c0];
        const float* wp = &w4.x;
#pragma unroll
        for (int ci=0;ci<4;ci++){ a[0][ci] += wp[ci]*xa; a[1][ci] += wp[ci]*xb; }
    }
    float4 bv = *(const float4*)&bias[c0];
    const float* bp = &bv.x;
#pragma unroll
    for (int pp=0;pp<2;pp++){
        int p = p0 + pg + pp*8;
        *(float4*)&Y[p*128+c0] = make_float4(a[pp][0]+bp[0], a[pp][1]+bp[1], a[pp][2]+bp[2], a[pp][3]+bp[3]);
    }
}

// l5: xv = sa_v @ sres + b  -> packed hi/lo bf16, layout [b][nchunk32][c128][n32]
//     xqk = sa_qk @ sres    -> packed hi/lo bf16, layout [n][32]
__global__ __launch_bounds__(256) void l5_kernel(const float* X, const float* WvT, const float* vb,
                                                 const float* WqkT, unsigned* xvt_pk, unsigned* xqk_pk){
    __shared__ float sx[16][128];
    int tid = threadIdx.x;
    int p0 = blockIdx.x * 16;
    for (int t = tid; t < 2048; t += 256) sx[t>>7][t&127] = X[p0*128 + t];
    __syncthreads();
    int cg = tid & 31, pg = tid >> 5, c0 = cg*4;
    {
        float a[2][4] = {{0,0,0,0},{0,0,0,0}};
        for (int j=0;j<128;j++){
            float xa = sx[pg][j], xb = sx[pg+8][j];
            float4 w4 = *(const float4*)&WvT[j*128 + c0];
            const float* wp = &w4.x;
#pragma unroll
            for (int ci=0;ci<4;ci++){ a[0][ci] += wp[ci]*xa; a[1][ci] += wp[ci]*xb; }
        }
        float4 bv = *(const float4*)&vb[c0];
        const float* bp = &bv.x;
#pragma unroll
        for (int pp=0;pp<2;pp++){
            int p = p0 + pg + pp*8;
            int bb = p >> 11, n = p & 2047;
            unsigned* dst = xvt_pk + ((size_t)(bb*64 + (n>>5)))*4096 + (n&31);
#pragma unroll
            for (int ci=0;ci<4;ci++) dst[(c0+ci)*32] = pack_hl(a[pp][ci] + bp[ci]);
        }
    }
    if (cg < 8){
        int cq = cg*4;
        float a[2][4] = {{0,0,0,0},{0,0,0,0}};
        for (int j=0;j<128;j++){
            float xa = sx[pg][j], xb = sx[pg+8][j];
            float4 w4 = *(const float4*)&WqkT[j*32 + cq];
            const float* wp = &w4.x;
#pragma unroll
            for (int ci=0;ci<4;ci++){ a[0][ci] += wp[ci]*xa; a[1][ci] += wp[ci]*xb; }
        }
#pragma unroll
        for (int pp=0;pp<2;pp++){
            int p = p0 + pg + pp*8;
            uint4 w;
            w.x = pack_hl(a[pp][0]); w.y = pack_hl(a[pp][1]);
            w.z = pack_hl(a[pp][2]); w.w = pack_hl(a[pp][3]);
            *(uint4*)&xqk_pk[p*32 + cq] = w;
        }
    }
}

// ---------------- batchnorm ----------------
__global__ void bn_stats_kernel(const float* X, float* sums){
    int tid = threadIdx.x;
    int c = tid & 127, half = tid >> 7;
    int r0 = blockIdx.x*128 + half*64;
    float s = 0.f, sq = 0.f;
    for (int r = r0; r < r0+64; r++){
        float v = X[r*128 + c];
        s += v; sq += v*v;
    }
    atomicAdd(&sums[c], s);
    atomicAdd(&sums[128+c], sq);
}

__global__ void bn1_apply_kernel(const float* res2, const float* x1, const float* sums,
                                 const float* g, const float* beta, float* sres){
    int gid = blockIdx.x*256 + threadIdx.x;
    int c = gid & 127;
    float mu = sums[c] * (1.0f/16384.f);
    float var = sums[128+c] * (1.0f/16384.f) - mu*mu;
    float inv = 1.0f / sqrtf(var + 1e-5f);
    float y = g[c]*(res2[gid]-mu)*inv + beta[c];
    sres[gid] = fmaxf(y, 0.f) + x1[gid];
}

__global__ void final_kernel(const float* sres, const float* xr2, const float* sums,
                             const float* g, const float* beta, float* out0){
    int gid = blockIdx.x*256 + threadIdx.x;
    int c = gid & 127;
    float mu = sums[c] * (1.0f/16384.f);
    float var = sums[128+c] * (1.0f/16384.f) - mu*mu;
    float inv = 1.0f / sqrtf(var + 1e-5f);
    float y = g[c]*(xr2[gid]-mu)*inv + beta[c];
    out0[gid] = sres[gid] + fmaxf(y, 0.f);
}

// ---------------- SA pass A: row max (hi-only) + exp-sum (3-product) via MFMA ----------------
__global__ __launch_bounds__(256) void sa_stats_kernel(const unsigned* xqk_pk, float* rm, float* irs){
    int tid = threadIdx.x;
    int lane = tid & 63, wave = tid >> 6;
    int b = blockIdx.x >> 5;
    int i0 = (blockIdx.x & 31) * 64 + wave*16;
    const unsigned* qb = xqk_pk + (size_t)b*2048*32;
    int quad = lane >> 4, l15 = lane & 15;
    const unsigned* ap = qb + (i0 + l15)*32 + quad*8;
    uint4 a0 = *(const uint4*)ap, a1 = *(const uint4*)(ap+4);
    short8 Ah, Al; split_hl(a0, a1, Ah, Al);

    float m[4] = {-3e38f,-3e38f,-3e38f,-3e38f};
    for (int jt=0; jt<128; jt++){
        const unsigned* bp = qb + (jt*16 + l15)*32 + quad*8;
        uint4 b0 = *(const uint4*)bp, b1 = *(const uint4*)(bp+4);
        short8 Bh, Bl; split_hl(b0,b1,Bh,Bl);
        f32x4 e = (f32x4){0.f,0.f,0.f,0.f};
        e = __builtin_amdgcn_mfma_f32_16x16x32_bf16(Ah, Bh, e, 0,0,0);
#pragma unroll
        for (int r=0;r<4;r++) m[r] = fmaxf(m[r], e[r]);
    }
#pragma unroll
    for (int mk=1; mk<16; mk<<=1)
#pragma unroll
        for (int r=0;r<4;r++) m[r] = fmaxf(m[r], __shfl_xor(m[r], mk));

    float s[4] = {0.f,0.f,0.f,0.f};
    for (int jt=0; jt<128; jt++){
        const unsigned* bp = qb + (jt*16 + l15)*32 + quad*8;
        uint4 b0 = *(const uint4*)bp, b1 = *(const uint4*)(bp+4);
        short8 Bh, Bl; split_hl(b0,b1,Bh,Bl);
        f32x4 e = e3_mfma(Ah,Al,Bh,Bl);
#pragma unroll
        for (int r=0;r<4;r++) s[r] += expf(e[r]-m[r]);
    }
#pragma unroll
    for (int mk=1; mk<16; mk<<=1)
#pragma unroll
        for (int r=0;r<4;r++) s[r] += __shfl_xor(s[r], mk);
    if (l15 == 0){
#pragma unroll
        for (int r=0;r<4;r++){
            int row = i0 + quad*4 + r;
            rm[b*2048+row]  = m[r];
            irs[b*2048+row] = 1.0f/s[r];
        }
    }
}

// ---------------- SA pass B: fused colsum + PV (flash-style), MFMA ----------------
#define SXV_STR 36
#define ATT_STR 36
__global__ __launch_bounds__(256) void sa_xr_kernel(const unsigned* xqk_pk, const unsigned* xvt_pk,
                                                    const float* rm, const float* irs, float* xr){
    __shared__ __align__(16) unsigned sxv[128*SXV_STR];   // 18432 B
    __shared__ __align__(16) unsigned attT[32*ATT_STR];   // 4608 B
    __shared__ float scs[2][2][16];
    __shared__ float scs2[32];
    int tid = threadIdx.x;
    int lane = tid & 63, wave = tid >> 6;
    int quad = lane >> 4, l15 = lane & 15;
    int b = blockIdx.x >> 6, mt = blockIdx.x & 63;
    int m0 = mt*32;
    int rt = wave >> 1, ct = wave & 1;
    const unsigned* qb = xqk_pk + (size_t)b*2048*32;

    // B-frags for this block's m-cols (energy), loaded once
    short8 Bmh, Bml;
    {
        const unsigned* bp = qb + (m0 + ct*16 + l15)*32 + quad*8;
        uint4 b0 = *(const uint4*)bp, b1 = *(const uint4*)(bp+4);
        split_hl(b0,b1,Bmh,Bml);
    }
    f32x4 acc[4];
#pragma unroll
    for (int cc=0;cc<4;cc++) acc[cc] = (f32x4){0.f,0.f,0.f,0.f};
    float cs_acc = 0.f;

    for (int chunk=0; chunk<64; chunk++){
        int n0 = chunk*32;
        __syncthreads();   // prev PV reads done
        // stage xv chunk -> LDS (packed hi/lo), [c][n] stride SXV_STR
        const unsigned* src = xvt_pk + ((size_t)(b*64 + chunk))*4096;
#pragma unroll
        for (int it=0; it<4; it++){
            int u = tid + it*256;
            int c = u >> 3, part = u & 7;
            *(uint4*)&sxv[c*SXV_STR + part*4] = *(const uint4*)(src + u*4);
        }
        // energy tile (rt, ct): rows n0+rt*16.., cols m0+ct*16..
        const unsigned* ap = qb + (n0 + rt*16 + l15)*32 + quad*8;
        uint4 a0 = *(const uint4*)ap, a1 = *(const uint4*)(ap+4);
        short8 Ah, Al; split_hl(a0,a1,Ah,Al);
        f32x4 e = e3_mfma(Ah,Al,Bmh,Bml);
        // att + colsum acc + write attT (packed hi/lo)
#pragma unroll
        for (int r=0;r<4;r++){
            int rowg = b*2048 + n0 + rt*16 + quad*4 + r;
            float att = expf(e[r] - rm[rowg]) * irs[rowg];
            cs_acc += att;
            attT[(ct*16+l15)*ATT_STR + rt*16 + quad*4 + r] = pack_hl(att);
        }
        __syncthreads();
        // PV: A = att^T (m-sub = ct), B = xv (c-subs rt*4..rt*4+3)
        const unsigned* arp = attT + (ct*16+l15)*ATT_STR + quad*8;
        uint4 aa0 = *(const uint4*)arp, aa1 = *(const uint4*)(arp+4);
        short8 Aph, Apl; split_hl(aa0,aa1,Aph,Apl);
#pragma unroll
        for (int cc=0; cc<4; cc++){
            int c0 = (rt*4 + cc)*16;
            const unsigned* xp = &sxv[(c0 + l15)*SXV_STR + quad*8];
            uint4 x0 = *(const uint4*)xp, x1 = *(const uint4*)(xp+4);
            short8 Xh, Xl; split_hl(x0,x1,Xh,Xl);
            acc[cc] = __builtin_amdgcn_mfma_f32_16x16x32_bf16(Apl, Xh, acc[cc], 0,0,0);
            acc[cc] = __builtin_amdgcn_mfma_f32_16x16x32_bf16(Aph, Xl, acc[cc], 0,0,0);
            acc[cc] = __builtin_amdgcn_mfma_f32_16x16x32_bf16(Aph, Xh, acc[cc], 0,0,0);
        }
    }
    // colsum: reduce across quads, combine rt halves, invert
    cs_acc += __shfl_xor(cs_acc, 16);
    cs_acc += __shfl_xor(cs_acc, 32);
    if (lane < 16) scs[ct][rt][lane] = cs_acc;
    __syncthreads();
    if (tid < 32) scs2[tid] = 1.0f / (1e-9f + scs[tid>>4][0][tid&15] + scs[tid>>4][1][tid&15]);
    __syncthreads();
    // scaled write: row m = m0+ct*16+quad*4+r, col = (rt*4+cc)*16+l15
#pragma unroll
    for (int cc=0; cc<4; cc++){
        int c0 = (rt*4 + cc)*16;
#pragma unroll
        for (int r=0;r<4;r++){
            int mloc = ct*16 + quad*4 + r;
            xr[(size_t)(b*2048 + m0 + mloc)*128 + c0 + l15] = acc[cc][r] * scs2[mloc];
        }
    }
}

// ---------------- launch ----------------
extern "C" void kernel_launch(void* const* d_in, const int* in_sizes, int n_in,
                              void* d_out, int out_size, void* d_ws, size_t ws_size,
                              hipStream_t stream){
    (void)in_sizes; (void)n_in; (void)out_size; (void)ws_size;
    const float* feat = (const float*)d_in[0];
    const float* fc1w = (const float*)d_in[1];  const float* fc1b = (const float*)d_in[2];
    const float* fc2w = (const float*)d_in[3];  const float* fc2b = (const float*)d_in[4];
    const float* bng  = (const float*)d_in[5];  const float* bnb  = (const float*)d_in[6];
    const float* fb1w = (const float*)d_in[7];  const float* fb1b = (const float*)d_in[8];
    const float* fb2w = (const float*)d_in[9];  const float* fb2b = (const float*)d_in[10];
    const float* fg1w = (const float*)d_in[11]; const float* fg1b = (const float*)d_in[12];
    const float* fg2w = (const float*)d_in[13]; const float* fg2b = (const float*)d_in[14];
    const float* wq   = (const float*)d_in[15]; const float* wk   = (const float*)d_in[16];
    const float* wv   = (const float*)d_in[17];
    const float* saqk = (const float*)d_in[18];
    const float* savw = (const float*)d_in[19]; const float* savb = (const float*)d_in[20];
    const float* satw = (const float*)d_in[21]; const float* satb = (const float*)d_in[22];
    const float* sabng= (const float*)d_in[23]; const float* sabnb= (const float*)d_in[24];

    float* out0 = (float*)d_out;
    float* out1 = out0 + 2097152;

    char* ws = (char*)d_ws;
    size_t off = 0;
    auto A = [&](size_t bytes)->char*{
        char* r = ws + off;
        off = (off + bytes + 255) & ~(size_t)255;
        return r;
    };
    const size_t PBUF = (size_t)NPTS*128*4;   // 8 MB
    int*      g_idx  = (int*)A((size_t)NPTS*KNN*4);
    float*    g_x1   = (float*)A(PBUF);
    float*    g_q    = (float*)A(PBUF);
    float*    g_k1   = (float*)A(PBUF);
    float*    g_v1   = (float*)A(PBUF);
    float*    g_res  = (float*)A(PBUF);
    float*    g_res2 = (float*)A(PBUF);
    float*    g_sres = (float*)A(PBUF);
    float*    g_xr   = (float*)A(PBUF);
    float*    g_xr2  = (float*)A(PBUF);
    unsigned* g_xvt_pk = (unsigned*)A((size_t)NPTS*128*4);   // 8 MB packed
    unsigned* g_xqk_pk = (unsigned*)A((size_t)NPTS*32*4);    // 2 MB packed
    float*    g_rm   = (float*)A((size_t)NPTS*4);
    float*    g_rs   = (float*)A((size_t)NPTS*4);            // holds 1/rs
    float*    g_stats= (float*)A((size_t)512*4);             // bn1(256) bn2(256)
    unsigned short* g_wpk = (unsigned short*)A((size_t)3*16384*2);
    float*    g_wqT  = (float*)A(65536);
    float*    g_wkT  = (float*)A(65536);
    float*    g_wvT  = (float*)A(65536);
    float*    g_fc2T = (float*)A(65536);
    float*    g_savT = (float*)A(65536);
    float*    g_satT = (float*)A(65536);
    float*    g_sqkT = (float*)A(16384);

    float* bn1s = g_stats;
    float* bn2s = g_stats + 256;

    hipMemsetAsync(g_stats, 0, (size_t)512*4, stream);

    pack_bfrag_kernel<<<192, 256, 0, stream>>>(fb2w, fg1w, fg2w, g_wpk);
    transpose_kernel<<<64, 256, 0, stream>>>(wq,   g_wqT, 128);
    transpose_kernel<<<64, 256, 0, stream>>>(wk,   g_wkT, 128);
    transpose_kernel<<<64, 256, 0, stream>>>(wv,   g_wvT, 128);
    transpose_kernel<<<64, 256, 0, stream>>>(fc2w, g_fc2T, 128);
    transpose_kernel<<<64, 256, 0, stream>>>(savw, g_savT, 128);
    transpose_kernel<<<64, 256, 0, stream>>>(satw, g_satT, 128);
    transpose_kernel<<<16, 256, 0, stream>>>(saqk, g_sqkT, 32);

    knn_kernel<<<512, 256, 0, stream>>>(feat, g_idx);
    x1_kernel<<<8192, 256, 0, stream>>>(feat, fc1w, fc1b, g_x1);
    qkv_kernel<<<1024, 256, 0, stream>>>(g_x1, g_wqT, g_wkT, g_wvT, g_q, g_k1, g_v1);
    attn_kernel<<<4096, 256, 0, stream>>>(feat, g_idx, g_q, g_k1, g_v1, g_wpk,
                                          fb1w, fb1b, fb2b, fg1b, fg2b, out1, g_res);
    lin_kernel<<<1024, 256, 0, stream>>>(g_res, g_fc2T, fc2b, g_res2);
    bn_stats_kernel<<<128, 256, 0, stream>>>(g_res2, bn1s);
    bn1_apply_kernel<<<8192, 256, 0, stream>>>(g_res2, g_x1, bn1s, bng, bnb, g_sres);
    l5_kernel<<<1024, 256, 0, stream>>>(g_sres, g_savT, savb, g_sqkT, g_xvt_pk, g_xqk_pk);
    sa_stats_kernel<<<256, 256, 0, stream>>>(g_xqk_pk, g_rm, g_rs);
    sa_xr_kernel<<<512, 256, 0, stream>>>(g_xqk_pk, g_xvt_pk, g_rm, g_rs, g_xr);
    l6_kernel<<<1024, 256, 0, stream>>>(g_sres, g_xr, g_satT, satb, g_xr2);
    bn_stats_kernel<<<128, 256, 0, stream>>>(g_xr2, bn2s);
    final_kernel<<<8192, 256, 0, stream>>>(g_sres, g_xr2, bn2s, sabng, sabnb, out0);
}